// Round 3
// 28596.921 us; speedup vs baseline: 1.0068x; 1.0068x over previous
//
#include <hip/hip_runtime.h>

#define TT 512
#define BB 64
#define IDIM 256
#define CDIM 512
#define NMEM 128
#define MDIM 64
#define KTOT 832     // (IDIM + M) + CDIM = 320 + 512
#define ODIM 576     // CDIM + M
#define NROWS 2048   // 4*CDIM

struct Params {
  const float* embs; const float* W_ih; const float* W_hh; const float* b_ih; const float* b_hh;
  const float* W_kr; const float* b_kr; const float* w_br; const float* W_kw; const float* b_kw;
  const float* w_bw; const float* W_e; const float* b_e; const float* W_a; const float* b_a;
  const float* h0; const float* c0; const float* r0; const float* mem0;
  float* out;
  unsigned* flags; // [256]: A-flags (phase A done count), [256..320): B-flags
  float* Wopt;   // [2048*832] reordered as [w][k][lr]
  float* h_buf;  // [2][B*CDIM] double buffered
  float* r_buf;  // [B*M]
};

__device__ __forceinline__ float sigmoidf_(float x) { return 1.0f / (1.0f + __expf(-x)); }
__device__ __forceinline__ float tanhf_(float x) {
  float e = __expf(-2.0f * fabsf(x));
  float t = (1.0f - e) / (1.0f + e);
  return copysignf(t, x);
}
__device__ __forceinline__ float softplusf_(float x) {
  return (x > 20.0f) ? x : log1pf(__expf(x));
}
__device__ __forceinline__ float wred_sum(float v) {
#pragma unroll
  for (int off = 32; off > 0; off >>= 1) v += __shfl_xor(v, off, 64);
  return v;
}
__device__ __forceinline__ float wred_max(float v) {
#pragma unroll
  for (int off = 32; off > 0; off >>= 1) v = fmaxf(v, __shfl_xor(v, off, 64));
  return v;
}
__device__ __forceinline__ unsigned wred_minu(unsigned v) {
#pragma unroll
  for (int off = 32; off > 0; off >>= 1) {
    unsigned o = (unsigned)__shfl_xor((int)v, off, 64);
    v = (o < v) ? o : v;
  }
  return v;
}

__device__ __forceinline__ unsigned flag_ld(const unsigned* f) {
  return __hip_atomic_load(f, __ATOMIC_RELAXED, __HIP_MEMORY_SCOPE_AGENT);
}

// Publish: one wbl2 (release, no inv) + one relaxed agent store to a PRIVATE word.
__device__ __forceinline__ void flag_release(unsigned* f, unsigned val) {
  __builtin_amdgcn_fence(__ATOMIC_RELEASE, "agent");   // buffer_wbl2 only
  __hip_atomic_store(f, val, __ATOMIC_RELAXED, __HIP_MEMORY_SCOPE_AGENT);
}

// Wave-0-only wait: poll A-flags (and optionally B-flags) until all >= target,
// then one acquire fence (buffer_inv). Caller must __syncthreads() after.
__device__ __forceinline__ void grid_wait(const unsigned* flags, int lane,
                                          unsigned target, bool withB) {
  const unsigned* fA = flags + lane * 4;
  const unsigned* fB = flags + 256 + lane;
  for (;;) {
    unsigned a0 = flag_ld(fA + 0);
    unsigned a1 = flag_ld(fA + 1);
    unsigned a2 = flag_ld(fA + 2);
    unsigned a3 = flag_ld(fA + 3);
    unsigned m = a0 < a1 ? a0 : a1;
    unsigned n = a2 < a3 ? a2 : a3;
    m = m < n ? m : n;
    if (withB) { unsigned b = flag_ld(fB); m = b < m ? b : m; }
    m = wred_minu(m);
    if (m >= target) break;
    __builtin_amdgcn_s_sleep(1);
  }
  __builtin_amdgcn_fence(__ATOMIC_ACQUIRE, "agent");   // buffer_inv only
}

// Pre-transpose combined weights into Wopt[(w*832 + k)*8 + lr],
// lr -> global gate row = 512*(lr>>1) + 2*w + (lr&1)
__global__ void __launch_bounds__(256) transpose_w_kernel(const float* __restrict__ W_ih,
                                                          const float* __restrict__ W_hh,
                                                          float* __restrict__ Wopt) {
  int idx = blockIdx.x * 256 + threadIdx.x;
  if (idx >= NROWS * KTOT) return;
  int lr = idx & 7;
  int rem = idx >> 3;          // w*832 + k
  int k = rem % KTOT;
  int w = rem / KTOT;
  int row = 512 * (lr >> 1) + 2 * w + (lr & 1);
  float v = (k < 320) ? W_ih[(size_t)row * 320 + k] : W_hh[(size_t)row * 512 + (k - 320)];
  Wopt[idx] = v;
}

__global__ void __launch_bounds__(256) mann_kernel(Params p) {
  const int w = blockIdx.x;       // 0..255 : owns c-dims {2w, 2w+1}
  const int tid = threadIdx.x;
  const int lane = tid & 63;
  const int q = tid >> 6;         // wave id 0..3

  // phase-A staging (xs aliased with cross-wave reduce buffer)
  __shared__ __align__(16) float xs[64 * 65];          // [kk][b] stride 65 (conflict-free)
  __shared__ __align__(16) float wsa[KTOT * 8];        // resident weights [k][lr]
  __shared__ float bsum[8];
  // phase-B (batch WGs only)
  __shared__ __align__(16) float Mem_s[MDIM][NMEM + 1];  // [m][n] stride 129 (conflict-free)
  __shared__ __align__(16) float hb[CDIM];
  __shared__ float kw_s[MDIM], kr_s[MDIM], e_s[MDIM], a_s[MDIM];
  __shared__ float ww_s[NMEM], wr_s[NMEM];
  __shared__ float sc[8];  // 0:betaw 1:betar 2:|kw| 3:|kr| 4,5:max parts 6,7:sum parts

  // ---------------- init ----------------
  {
    const float4* src = (const float4*)(p.Wopt + (size_t)w * KTOT * 8);
    float4* dst = (float4*)wsa;
    for (int i = tid; i < KTOT * 2; i += 256) dst[i] = src[i];
  }
  if (tid < 8) {
    int row = 512 * (tid >> 1) + 2 * w + (tid & 1);
    bsum[tid] = p.b_ih[row] + p.b_hh[row];
  }
  float c_reg = 0.0f;  // valid for tid<128: cell state for (b=tid&63, j=2w+(tid>>6))
  if (tid < 128) {
    int jj = tid >> 6, b = tid & 63;
    int j = 2 * w + jj;
    c_reg = p.c0[j];
    p.h_buf[(size_t)b * CDIM + j] = p.h0[j];  // h_buf[0]
  }
  if (w < BB) {
    for (int idx = tid; idx < NMEM * MDIM; idx += 256) {
      int n = idx >> 6, m = idx & 63;
      Mem_s[m][n] = p.mem0[idx];  // mem0[n][m] -> Mem_s[m][n]
    }
    if (tid < MDIM) p.r_buf[w * MDIM + tid] = p.r0[tid];
  }
  __syncthreads();
  if (tid == 0) {
    __builtin_amdgcn_fence(__ATOMIC_RELEASE, "agent");
    __hip_atomic_store(&p.flags[w], 1u, __ATOMIC_RELAXED, __HIP_MEMORY_SCOPE_AGENT);
    if (w < BB)
      __hip_atomic_store(&p.flags[256 + w], 1u, __ATOMIC_RELAXED, __HIP_MEMORY_SCOPE_AGENT);
  }

#pragma unroll 1
  for (int t = 0; t < TT; ++t) {
    // ---- step entry: h(t) buffer + r(t) ready, and prior readers of our
    //      h_write buffer are done (A >= t+1 and B >= t+1) ----
    if (tid < 64) grid_wait(p.flags, lane, (unsigned)(t + 1), true);
    __syncthreads();

    const float* h_read = p.h_buf + (size_t)(t & 1) * (BB * CDIM);
    float* h_write = p.h_buf + (size_t)((t + 1) & 1) * (BB * CDIM);

    // ---------------- Phase A: gates GEMM + LSTM ----------------
    float acc[8];
#pragma unroll
    for (int i = 0; i < 8; ++i) acc[i] = 0.0f;

    const int kk4 = (tid & 15) * 4;
    const int bb0 = tid >> 4;

    // prefetch chunk 0 (x-slice) into registers; weights are LDS-resident
    float4 vbuf[4];
    {
      const int k = kk4;  // chunk 0 -> embs
#pragma unroll
      for (int i = 0; i < 4; ++i) {
        const int b = bb0 + 16 * i;
        vbuf[i] = *(const float4*)(p.embs + ((size_t)t * BB + b) * IDIM + k);
      }
    }

#pragma unroll 1
    for (int c = 0; c < 13; ++c) {
      // store prefetched x chunk to LDS
#pragma unroll
      for (int i = 0; i < 4; ++i) {
        const int b = bb0 + 16 * i;
        xs[(kk4 + 0) * 65 + b] = vbuf[i].x;
        xs[(kk4 + 1) * 65 + b] = vbuf[i].y;
        xs[(kk4 + 2) * 65 + b] = vbuf[i].z;
        xs[(kk4 + 3) * 65 + b] = vbuf[i].w;
      }
      __syncthreads();

      // issue next chunk's global loads (overlap with compute below)
      if (c < 12) {
        const int cn = c + 1;
        const int k = cn * 64 + kk4;
#pragma unroll
        for (int i = 0; i < 4; ++i) {
          const int b = bb0 + 16 * i;
          if (cn < 4)       vbuf[i] = *(const float4*)(p.embs + ((size_t)t * BB + b) * IDIM + k);
          else if (cn == 4) vbuf[i] = *(const float4*)(p.r_buf + b * MDIM + (k - 256));
          else              vbuf[i] = *(const float4*)(h_read + (size_t)b * CDIM + (k - 320));
        }
      }

      // wave q computes kk in [16q, 16q+16) for all 8 rows (K-split across waves)
      const int kkb = 16 * q;
#pragma unroll
      for (int kki = 0; kki < 16; ++kki) {
        const int kk = kkb + kki;
        const float xv = xs[kk * 65 + lane];
        const float4 w0 = *(const float4*)&wsa[(c * 64 + kk) * 8];
        const float4 w1 = *(const float4*)&wsa[(c * 64 + kk) * 8 + 4];
        acc[0] = fmaf(xv, w0.x, acc[0]);
        acc[1] = fmaf(xv, w0.y, acc[1]);
        acc[2] = fmaf(xv, w0.z, acc[2]);
        acc[3] = fmaf(xv, w0.w, acc[3]);
        acc[4] = fmaf(xv, w1.x, acc[4]);
        acc[5] = fmaf(xv, w1.y, acc[5]);
        acc[6] = fmaf(xv, w1.z, acc[6]);
        acc[7] = fmaf(xv, w1.w, acc[7]);
      }
      __syncthreads();
    }
    // cross-wave K reduction (reuse xs region)
    {
      float* red = xs;  // [q][lr][b] = [4][8][64]
#pragma unroll
      for (int lr = 0; lr < 8; ++lr) red[(q * 8 + lr) * 64 + lane] = acc[lr];
      __syncthreads();
      if (tid < 128) {
        const int jj = tid >> 6, b = tid & 63;
        float g[4];
#pragma unroll
        for (int gate = 0; gate < 4; ++gate) {
          const int lr = gate * 2 + jj;
          float s = bsum[lr];
#pragma unroll
          for (int qq = 0; qq < 4; ++qq) s += red[(qq * 8 + lr) * 64 + b];
          g[gate] = s;
        }
        const float iv = sigmoidf_(g[0]);
        const float fv = sigmoidf_(g[1]);
        const float gv = tanhf_(g[2]);
        const float ov = sigmoidf_(g[3]);
        c_reg = fv * c_reg + iv * gv;
        const float hv = ov * tanhf_(c_reg);
        h_write[(size_t)b * CDIM + 2 * w + jj] = hv;
      }
    }
    // ---- publish phase A (private flag, no contention) ----
    __syncthreads();
    if (tid == 0) flag_release(&p.flags[w], (unsigned)(t + 2));

    // ---------------- Phase B: heads + addressing + memory (batch WGs) ----------------
    if (w < BB) {
      // wait for ALL producers' h(t) slices
      if (tid < 64) grid_wait(p.flags, lane, (unsigned)(t + 2), false);
      __syncthreads();

      const int b = w;
      hb[tid] = h_write[(size_t)b * CDIM + tid];
      hb[tid + 256] = h_write[(size_t)b * CDIM + tid + 256];
      __syncthreads();
      // head GEMVs: [0,64):kw  [64,128):e  [128,192):kr  192:betaw 193:betar
      if (tid < 194) {
        const float* Wrow;
        if (tid < 64)        Wrow = p.W_kw + (size_t)tid * CDIM;
        else if (tid < 128)  Wrow = p.W_e + (size_t)(tid - 64) * CDIM;
        else if (tid < 192)  Wrow = p.W_kr + (size_t)(tid - 128) * CDIM;
        else if (tid == 192) Wrow = p.w_bw;
        else                 Wrow = p.w_br;
        float s = 0.0f;
#pragma unroll 4
        for (int k = 0; k < CDIM; k += 4) {
          const float4 wv = *(const float4*)(Wrow + k);
          s = fmaf(wv.x, hb[k], s);
          s = fmaf(wv.y, hb[k + 1], s);
          s = fmaf(wv.z, hb[k + 2], s);
          s = fmaf(wv.w, hb[k + 3], s);
        }
        if (tid < 64)       kw_s[tid] = tanhf_(s + p.b_kw[tid]);
        else if (tid < 128) e_s[tid - 64] = sigmoidf_(s + p.b_e[tid - 64]);
        else if (tid < 192) kr_s[tid - 128] = tanhf_(s + p.b_kr[tid - 128]);
        else                sc[tid - 192] = softplusf_(s);
      }
      // a = tanh(emb @ W_a^T + b_a)
      if (tid < 64) {
        const float* Wrow = p.W_a + (size_t)tid * IDIM;
        const float* eb = p.embs + ((size_t)t * BB + b) * IDIM;
        float s = p.b_a[tid];
#pragma unroll 4
        for (int k = 0; k < IDIM; k += 4) {
          const float4 wv = *(const float4*)(Wrow + k);
          const float4 ev = *(const float4*)(eb + k);
          s = fmaf(wv.x, ev.x, s);
          s = fmaf(wv.y, ev.y, s);
          s = fmaf(wv.z, ev.z, s);
          s = fmaf(wv.w, ev.w, s);
        }
        a_s[tid] = tanhf_(s);
      }
      __syncthreads();
      // key norms: wave0 -> |kw|, wave1 -> |kr|
      if (tid < 128) {
        const float v = (q == 0) ? kw_s[lane] : kr_s[lane];
        const float ss = wred_sum(v * v);
        if (lane == 0) sc[2 + q] = sqrtf(ss);
      }
      __syncthreads();
      // ---- write addressing (on old Mem) ----
      {
        float logit = 0.0f, ex = 0.0f;
        const float beta = sc[0], keyn = sc[2];
        if (tid < 128) {
          float sim = 0.0f, nrm = 0.0f;
#pragma unroll 8
          for (int m = 0; m < MDIM; ++m) {
            const float mv = Mem_s[m][tid];
            sim = fmaf(mv, kw_s[m], sim);
            nrm = fmaf(mv, mv, nrm);
          }
          logit = beta * sim / (sqrtf(nrm) * keyn + 1e-8f);
          const float mx = wred_max(logit);
          if (lane == 0) sc[4 + q] = mx;
        }
        __syncthreads();
        if (tid < 128) {
          ex = __expf(logit - fmaxf(sc[4], sc[5]));
          const float sm = wred_sum(ex);
          if (lane == 0) sc[6 + q] = sm;
        }
        __syncthreads();
        if (tid < 128) ww_s[tid] = ex / (sc[6] + sc[7]);
        __syncthreads();
      }
      // ---- memory write (erase/add) ----
      for (int idx = tid; idx < NMEM * MDIM; idx += 256) {
        const int m = idx >> 7, n = idx & 127;
        const float mv = Mem_s[m][n];
        Mem_s[m][n] = mv * (1.0f - ww_s[n] * e_s[m]) + ww_s[n] * a_s[m];
      }
      __syncthreads();
      // ---- read addressing (on new Mem) ----
      {
        float logit = 0.0f, ex = 0.0f;
        const float beta = sc[1], keyn = sc[3];
        if (tid < 128) {
          float sim = 0.0f, nrm = 0.0f;
#pragma unroll 8
          for (int m = 0; m < MDIM; ++m) {
            const float mv = Mem_s[m][tid];
            sim = fmaf(mv, kr_s[m], sim);
            nrm = fmaf(mv, mv, nrm);
          }
          logit = beta * sim / (sqrtf(nrm) * keyn + 1e-8f);
          const float mx = wred_max(logit);
          if (lane == 0) sc[4 + q] = mx;
        }
        __syncthreads();
        if (tid < 128) {
          ex = __expf(logit - fmaxf(sc[4], sc[5]));
          const float sm = wred_sum(ex);
          if (lane == 0) sc[6 + q] = sm;
        }
        __syncthreads();
        if (tid < 128) wr_s[tid] = ex / (sc[6] + sc[7]);
        __syncthreads();
      }
      // ---- read vector + outputs ----
      if (tid < 64) {
        float rv = 0.0f;
#pragma unroll 8
        for (int n = 0; n < NMEM; ++n) rv = fmaf(wr_s[n], Mem_s[tid][n], rv);
        p.r_buf[b * MDIM + tid] = rv;
        p.out[((size_t)t * BB + b) * ODIM + 512 + tid] = rv;
      }
      p.out[((size_t)t * BB + b) * ODIM + tid] = hb[tid];
      p.out[((size_t)t * BB + b) * ODIM + 256 + tid] = hb[tid + 256];
      // ---- publish phase B (private flag) ----
      __syncthreads();
      if (tid == 0) flag_release(&p.flags[256 + w], (unsigned)(t + 2));
    }
  }
}

extern "C" void kernel_launch(void* const* d_in, const int* in_sizes, int n_in,
                              void* d_out, int out_size, void* d_ws, size_t ws_size,
                              hipStream_t stream) {
  (void)in_sizes; (void)n_in; (void)out_size; (void)ws_size;
  Params p;
  p.embs = (const float*)d_in[0];
  p.W_ih = (const float*)d_in[1];
  p.W_hh = (const float*)d_in[2];
  p.b_ih = (const float*)d_in[3];
  p.b_hh = (const float*)d_in[4];
  p.W_kr = (const float*)d_in[5];
  p.b_kr = (const float*)d_in[6];
  p.w_br = (const float*)d_in[7];
  p.W_kw = (const float*)d_in[8];
  p.b_kw = (const float*)d_in[9];
  p.w_bw = (const float*)d_in[10];
  p.W_e  = (const float*)d_in[11];
  p.b_e  = (const float*)d_in[12];
  p.W_a  = (const float*)d_in[13];
  p.b_a  = (const float*)d_in[14];
  p.h0   = (const float*)d_in[15];
  p.c0   = (const float*)d_in[16];
  p.r0   = (const float*)d_in[17];
  p.mem0 = (const float*)d_in[18];
  p.out = (float*)d_out;

  float* ws = (float*)d_ws;
  p.flags = (unsigned*)ws;                  // 320 uints used, 512 reserved
  p.Wopt = ws + 512;                        // 2048*832      = 1,703,936 floats
  p.h_buf = p.Wopt + (size_t)NROWS * KTOT;  // 2*64*512      = 65,536 floats
  p.r_buf = p.h_buf + 2 * BB * CDIM;        // 64*64         = 4,096 floats

  hipMemsetAsync(p.flags, 0, 512 * sizeof(unsigned), stream);

  const int total = NROWS * KTOT;
  hipLaunchKernelGGL(transpose_w_kernel, dim3((total + 255) / 256), dim3(256), 0, stream,
                     p.W_ih, p.W_hh, p.Wopt);

  void* kargs[] = { (void*)&p };
  hipLaunchCooperativeKernel((const void*)mann_kernel, dim3(256), dim3(256), kargs, 0, stream);
}

// Round 4
// 24809.399 us; speedup vs baseline: 1.1605x; 1.1527x over previous
//
#include <hip/hip_runtime.h>

#define TT 512
#define BB 64
#define IDIM 256
#define CDIM 512
#define NMEM 128
#define MDIM 64
#define KTOT 832     // (IDIM + M) + CDIM = 320 + 512
#define ODIM 576     // CDIM + M
#define NROWS 2048   // 4*CDIM

struct Params {
  const float* embs; const float* W_ih; const float* W_hh; const float* b_ih; const float* b_hh;
  const float* W_kr; const float* b_kr; const float* w_br; const float* W_kw; const float* b_kw;
  const float* w_bw; const float* W_e; const float* b_e; const float* W_a; const float* b_a;
  const float* h0; const float* c0; const float* r0; const float* mem0;
  float* out;
  unsigned* flags; // [256]: A-flags (phase A done count), [256..320): B-flags
  float* Wopt;   // [2048*832] reordered as [w][k][lr]
  float* h_buf;  // [2][B*CDIM] double buffered (written ONLY via agent atomics)
  float* r_buf;  // [B*M]                      (written ONLY via agent atomics)
};

__device__ __forceinline__ float sigmoidf_(float x) { return 1.0f / (1.0f + __expf(-x)); }
__device__ __forceinline__ float tanhf_(float x) {
  float e = __expf(-2.0f * fabsf(x));
  float t = (1.0f - e) / (1.0f + e);
  return copysignf(t, x);
}
__device__ __forceinline__ float softplusf_(float x) {
  return (x > 20.0f) ? x : log1pf(__expf(x));
}
__device__ __forceinline__ float wred_sum(float v) {
#pragma unroll
  for (int off = 32; off > 0; off >>= 1) v += __shfl_xor(v, off, 64);
  return v;
}
__device__ __forceinline__ float wred_max(float v) {
#pragma unroll
  for (int off = 32; off > 0; off >>= 1) v = fmaxf(v, __shfl_xor(v, off, 64));
  return v;
}
__device__ __forceinline__ unsigned wred_minu(unsigned v) {
#pragma unroll
  for (int off = 32; off > 0; off >>= 1) {
    unsigned o = (unsigned)__shfl_xor((int)v, off, 64);
    v = (o < v) ? o : v;
  }
  return v;
}

__device__ __forceinline__ unsigned flag_ld(const unsigned* f) {
  return __hip_atomic_load(f, __ATOMIC_RELAXED, __HIP_MEMORY_SCOPE_AGENT);
}
// Write-through store to the coherence point (same mechanism as the flag words).
__device__ __forceinline__ void st_wt(float* p, float v) {
  __hip_atomic_store(p, v, __ATOMIC_RELAXED, __HIP_MEMORY_SCOPE_AGENT);
}
// Publish: data was written via st_wt and drained (vmcnt0 + barrier) -> just store flag.
__device__ __forceinline__ void flag_post(unsigned* f, unsigned val) {
  __hip_atomic_store(f, val, __ATOMIC_RELAXED, __HIP_MEMORY_SCOPE_AGENT);
}
__device__ __forceinline__ void drain_vm() {
  asm volatile("s_waitcnt vmcnt(0)" ::: "memory");
}

// Wave-0-only wait: poll A-flags (and optionally B-flags) until all >= target,
// then one acquire fence (buffer_inv). Caller must __syncthreads() after.
__device__ __forceinline__ void grid_wait(const unsigned* flags, int lane,
                                          unsigned target, bool withB) {
  const unsigned* fA = flags + lane * 4;
  const unsigned* fB = flags + 256 + lane;
  for (;;) {
    unsigned a0 = flag_ld(fA + 0);
    unsigned a1 = flag_ld(fA + 1);
    unsigned a2 = flag_ld(fA + 2);
    unsigned a3 = flag_ld(fA + 3);
    unsigned m = a0 < a1 ? a0 : a1;
    unsigned n = a2 < a3 ? a2 : a3;
    m = m < n ? m : n;
    if (withB) { unsigned b = flag_ld(fB); m = b < m ? b : m; }
    m = wred_minu(m);
    if (m >= target) break;
    __builtin_amdgcn_s_sleep(1);
  }
  __builtin_amdgcn_fence(__ATOMIC_ACQUIRE, "agent");   // buffer_inv only
}

// Pre-transpose combined weights into Wopt[(w*832 + k)*8 + lr],
// lr -> global gate row = 512*(lr>>1) + 2*w + (lr&1)
__global__ void __launch_bounds__(256) transpose_w_kernel(const float* __restrict__ W_ih,
                                                          const float* __restrict__ W_hh,
                                                          float* __restrict__ Wopt) {
  int idx = blockIdx.x * 256 + threadIdx.x;
  if (idx >= NROWS * KTOT) return;
  int lr = idx & 7;
  int rem = idx >> 3;          // w*832 + k
  int k = rem % KTOT;
  int w = rem / KTOT;
  int row = 512 * (lr >> 1) + 2 * w + (lr & 1);
  float v = (k < 320) ? W_ih[(size_t)row * 320 + k] : W_hh[(size_t)row * 512 + (k - 320)];
  Wopt[idx] = v;
}

__global__ void __launch_bounds__(256) mann_kernel(Params p) {
  const int w = blockIdx.x;       // 0..255 : owns c-dims {2w, 2w+1}
  const int tid = threadIdx.x;
  const int lane = tid & 63;
  const int q = tid >> 6;         // wave id 0..3

  // phase-A staging (xs aliased with cross-wave reduce buffer)
  __shared__ __align__(16) float xs[64 * 65];          // [kk][b] stride 65 (conflict-free)
  __shared__ __align__(16) float wsa[KTOT * 8];        // resident weights [k][lr]
  __shared__ float bsum[8];
  // phase-B (batch WGs only)
  __shared__ __align__(16) float Mem_s[MDIM][NMEM + 1];  // [m][n] stride 129 (conflict-free)
  __shared__ __align__(16) float hb[CDIM];
  __shared__ float kw_s[MDIM], kr_s[MDIM], e_s[MDIM], a_s[MDIM];
  __shared__ float ww_s[NMEM], wr_s[NMEM];
  __shared__ float sc[8];  // 0:betaw 1:betar 2:|kw| 3:|kr| 4,5:max parts 6,7:sum parts

  // ---------------- init ----------------
  {
    const float4* src = (const float4*)(p.Wopt + (size_t)w * KTOT * 8);
    float4* dst = (float4*)wsa;
    for (int i = tid; i < KTOT * 2; i += 256) dst[i] = src[i];
  }
  if (tid < 8) {
    int row = 512 * (tid >> 1) + 2 * w + (tid & 1);
    bsum[tid] = p.b_ih[row] + p.b_hh[row];
  }
  float c_reg = 0.0f;  // valid for tid<128: cell state for (b=tid&63, j=2w+(tid>>6))
  if (tid < 128) {
    int jj = tid >> 6, b = tid & 63;
    int j = 2 * w + jj;
    c_reg = p.c0[j];
    st_wt(p.h_buf + (size_t)b * CDIM + j, p.h0[j]);  // h_buf[0]
  }
  if (w < BB) {
    for (int idx = tid; idx < NMEM * MDIM; idx += 256) {
      int n = idx >> 6, m = idx & 63;
      Mem_s[m][n] = p.mem0[idx];  // mem0[n][m] -> Mem_s[m][n]
    }
    if (tid < MDIM) st_wt(p.r_buf + w * MDIM + tid, p.r0[tid]);
  }
  drain_vm();
  __syncthreads();
  if (tid == 0) {
    flag_post(&p.flags[w], 1u);
    if (w < BB) flag_post(&p.flags[256 + w], 1u);
  }

#pragma unroll 1
  for (int t = 0; t < TT; ++t) {
    // ---- step entry: h(t) buffer + r(t) ready, and prior readers of our
    //      h_write buffer are done (A >= t+1 and B >= t+1) ----
    if (tid < 64) grid_wait(p.flags, lane, (unsigned)(t + 1), true);
    __syncthreads();

    const float* h_read = p.h_buf + (size_t)(t & 1) * (BB * CDIM);
    float* h_write = p.h_buf + (size_t)((t + 1) & 1) * (BB * CDIM);

    // ---------------- Phase A: gates GEMM + LSTM ----------------
    float acc[8];
#pragma unroll
    for (int i = 0; i < 8; ++i) acc[i] = 0.0f;

    const int kk4 = (tid & 15) * 4;
    const int bb0 = tid >> 4;

    // prefetch chunk 0 (x-slice) into registers; weights are LDS-resident
    float4 vbuf[4];
    {
      const int k = kk4;  // chunk 0 -> embs
#pragma unroll
      for (int i = 0; i < 4; ++i) {
        const int b = bb0 + 16 * i;
        vbuf[i] = *(const float4*)(p.embs + ((size_t)t * BB + b) * IDIM + k);
      }
    }

#pragma unroll 1
    for (int c = 0; c < 13; ++c) {
      // store prefetched x chunk to LDS
#pragma unroll
      for (int i = 0; i < 4; ++i) {
        const int b = bb0 + 16 * i;
        xs[(kk4 + 0) * 65 + b] = vbuf[i].x;
        xs[(kk4 + 1) * 65 + b] = vbuf[i].y;
        xs[(kk4 + 2) * 65 + b] = vbuf[i].z;
        xs[(kk4 + 3) * 65 + b] = vbuf[i].w;
      }
      __syncthreads();

      // issue next chunk's global loads (overlap with compute below)
      if (c < 12) {
        const int cn = c + 1;
        const int k = cn * 64 + kk4;
#pragma unroll
        for (int i = 0; i < 4; ++i) {
          const int b = bb0 + 16 * i;
          if (cn < 4)       vbuf[i] = *(const float4*)(p.embs + ((size_t)t * BB + b) * IDIM + k);
          else if (cn == 4) vbuf[i] = *(const float4*)(p.r_buf + b * MDIM + (k - 256));
          else              vbuf[i] = *(const float4*)(h_read + (size_t)b * CDIM + (k - 320));
        }
      }

      // wave q computes kk in [16q, 16q+16) for all 8 rows (K-split across waves)
      const int kkb = 16 * q;
#pragma unroll
      for (int kki = 0; kki < 16; ++kki) {
        const int kk = kkb + kki;
        const float xv = xs[kk * 65 + lane];
        const float4 w0 = *(const float4*)&wsa[(c * 64 + kk) * 8];
        const float4 w1 = *(const float4*)&wsa[(c * 64 + kk) * 8 + 4];
        acc[0] = fmaf(xv, w0.x, acc[0]);
        acc[1] = fmaf(xv, w0.y, acc[1]);
        acc[2] = fmaf(xv, w0.z, acc[2]);
        acc[3] = fmaf(xv, w0.w, acc[3]);
        acc[4] = fmaf(xv, w1.x, acc[4]);
        acc[5] = fmaf(xv, w1.y, acc[5]);
        acc[6] = fmaf(xv, w1.z, acc[6]);
        acc[7] = fmaf(xv, w1.w, acc[7]);
      }
      __syncthreads();
    }
    // cross-wave K reduction (reuse xs region)
    {
      float* red = xs;  // [q][lr][b] = [4][8][64]
#pragma unroll
      for (int lr = 0; lr < 8; ++lr) red[(q * 8 + lr) * 64 + lane] = acc[lr];
      __syncthreads();
      if (tid < 128) {
        const int jj = tid >> 6, b = tid & 63;
        float g[4];
#pragma unroll
        for (int gate = 0; gate < 4; ++gate) {
          const int lr = gate * 2 + jj;
          float s = bsum[lr];
#pragma unroll
          for (int qq = 0; qq < 4; ++qq) s += red[(qq * 8 + lr) * 64 + b];
          g[gate] = s;
        }
        const float iv = sigmoidf_(g[0]);
        const float fv = sigmoidf_(g[1]);
        const float gv = tanhf_(g[2]);
        const float ov = sigmoidf_(g[3]);
        c_reg = fv * c_reg + iv * gv;
        const float hv = ov * tanhf_(c_reg);
        st_wt(h_write + (size_t)b * CDIM + 2 * w + jj, hv);
      }
    }
    // ---- publish phase A: write-through data drained, then private flag ----
    drain_vm();
    __syncthreads();
    if (tid == 0) flag_post(&p.flags[w], (unsigned)(t + 2));

    // ---------------- Phase B: heads + addressing + memory (batch WGs) ----------------
    if (w < BB) {
      // wait for ALL producers' h(t) slices
      if (tid < 64) grid_wait(p.flags, lane, (unsigned)(t + 2), false);
      __syncthreads();

      const int b = w;
      hb[tid] = h_write[(size_t)b * CDIM + tid];
      hb[tid + 256] = h_write[(size_t)b * CDIM + tid + 256];
      __syncthreads();
      // head GEMVs: [0,64):kw  [64,128):e  [128,192):kr  192:betaw 193:betar
      if (tid < 194) {
        const float* Wrow;
        if (tid < 64)        Wrow = p.W_kw + (size_t)tid * CDIM;
        else if (tid < 128)  Wrow = p.W_e + (size_t)(tid - 64) * CDIM;
        else if (tid < 192)  Wrow = p.W_kr + (size_t)(tid - 128) * CDIM;
        else if (tid == 192) Wrow = p.w_bw;
        else                 Wrow = p.w_br;
        float s = 0.0f;
#pragma unroll 4
        for (int k = 0; k < CDIM; k += 4) {
          const float4 wv = *(const float4*)(Wrow + k);
          s = fmaf(wv.x, hb[k], s);
          s = fmaf(wv.y, hb[k + 1], s);
          s = fmaf(wv.z, hb[k + 2], s);
          s = fmaf(wv.w, hb[k + 3], s);
        }
        if (tid < 64)       kw_s[tid] = tanhf_(s + p.b_kw[tid]);
        else if (tid < 128) e_s[tid - 64] = sigmoidf_(s + p.b_e[tid - 64]);
        else if (tid < 192) kr_s[tid - 128] = tanhf_(s + p.b_kr[tid - 128]);
        else                sc[tid - 192] = softplusf_(s);
      }
      // a = tanh(emb @ W_a^T + b_a)
      if (tid < 64) {
        const float* Wrow = p.W_a + (size_t)tid * IDIM;
        const float* eb = p.embs + ((size_t)t * BB + b) * IDIM;
        float s = p.b_a[tid];
#pragma unroll 4
        for (int k = 0; k < IDIM; k += 4) {
          const float4 wv = *(const float4*)(Wrow + k);
          const float4 ev = *(const float4*)(eb + k);
          s = fmaf(wv.x, ev.x, s);
          s = fmaf(wv.y, ev.y, s);
          s = fmaf(wv.z, ev.z, s);
          s = fmaf(wv.w, ev.w, s);
        }
        a_s[tid] = tanhf_(s);
      }
      __syncthreads();
      // key norms: wave0 -> |kw|, wave1 -> |kr|
      if (tid < 128) {
        const float v = (q == 0) ? kw_s[lane] : kr_s[lane];
        const float ss = wred_sum(v * v);
        if (lane == 0) sc[2 + q] = sqrtf(ss);
      }
      __syncthreads();
      // ---- write addressing (on old Mem) ----
      {
        float logit = 0.0f, ex = 0.0f;
        const float beta = sc[0], keyn = sc[2];
        if (tid < 128) {
          float sim = 0.0f, nrm = 0.0f;
#pragma unroll 8
          for (int m = 0; m < MDIM; ++m) {
            const float mv = Mem_s[m][tid];
            sim = fmaf(mv, kw_s[m], sim);
            nrm = fmaf(mv, mv, nrm);
          }
          logit = beta * sim / (sqrtf(nrm) * keyn + 1e-8f);
          const float mx = wred_max(logit);
          if (lane == 0) sc[4 + q] = mx;
        }
        __syncthreads();
        if (tid < 128) {
          ex = __expf(logit - fmaxf(sc[4], sc[5]));
          const float sm = wred_sum(ex);
          if (lane == 0) sc[6 + q] = sm;
        }
        __syncthreads();
        if (tid < 128) ww_s[tid] = ex / (sc[6] + sc[7]);
        __syncthreads();
      }
      // ---- memory write (erase/add) ----
      for (int idx = tid; idx < NMEM * MDIM; idx += 256) {
        const int m = idx >> 7, n = idx & 127;
        const float mv = Mem_s[m][n];
        Mem_s[m][n] = mv * (1.0f - ww_s[n] * e_s[m]) + ww_s[n] * a_s[m];
      }
      __syncthreads();
      // ---- read addressing (on new Mem) ----
      {
        float logit = 0.0f, ex = 0.0f;
        const float beta = sc[1], keyn = sc[3];
        if (tid < 128) {
          float sim = 0.0f, nrm = 0.0f;
#pragma unroll 8
          for (int m = 0; m < MDIM; ++m) {
            const float mv = Mem_s[m][tid];
            sim = fmaf(mv, kr_s[m], sim);
            nrm = fmaf(mv, mv, nrm);
          }
          logit = beta * sim / (sqrtf(nrm) * keyn + 1e-8f);
          const float mx = wred_max(logit);
          if (lane == 0) sc[4 + q] = mx;
        }
        __syncthreads();
        if (tid < 128) {
          ex = __expf(logit - fmaxf(sc[4], sc[5]));
          const float sm = wred_sum(ex);
          if (lane == 0) sc[6 + q] = sm;
        }
        __syncthreads();
        if (tid < 128) wr_s[tid] = ex / (sc[6] + sc[7]);
        __syncthreads();
      }
      // ---- read vector + outputs ----
      if (tid < 64) {
        float rv = 0.0f;
#pragma unroll 8
        for (int n = 0; n < NMEM; ++n) rv = fmaf(wr_s[n], Mem_s[tid][n], rv);
        st_wt(p.r_buf + b * MDIM + tid, rv);
        p.out[((size_t)t * BB + b) * ODIM + 512 + tid] = rv;
      }
      p.out[((size_t)t * BB + b) * ODIM + tid] = hb[tid];
      p.out[((size_t)t * BB + b) * ODIM + 256 + tid] = hb[tid + 256];
      // ---- publish phase B (write-through drained, then private flag) ----
      drain_vm();
      __syncthreads();
      if (tid == 0) flag_post(&p.flags[256 + w], (unsigned)(t + 2));
    }
  }
}

extern "C" void kernel_launch(void* const* d_in, const int* in_sizes, int n_in,
                              void* d_out, int out_size, void* d_ws, size_t ws_size,
                              hipStream_t stream) {
  (void)in_sizes; (void)n_in; (void)out_size; (void)ws_size;
  Params p;
  p.embs = (const float*)d_in[0];
  p.W_ih = (const float*)d_in[1];
  p.W_hh = (const float*)d_in[2];
  p.b_ih = (const float*)d_in[3];
  p.b_hh = (const float*)d_in[4];
  p.W_kr = (const float*)d_in[5];
  p.b_kr = (const float*)d_in[6];
  p.w_br = (const float*)d_in[7];
  p.W_kw = (const float*)d_in[8];
  p.b_kw = (const float*)d_in[9];
  p.w_bw = (const float*)d_in[10];
  p.W_e  = (const float*)d_in[11];
  p.b_e  = (const float*)d_in[12];
  p.W_a  = (const float*)d_in[13];
  p.b_a  = (const float*)d_in[14];
  p.h0   = (const float*)d_in[15];
  p.c0   = (const float*)d_in[16];
  p.r0   = (const float*)d_in[17];
  p.mem0 = (const float*)d_in[18];
  p.out = (float*)d_out;

  float* ws = (float*)d_ws;
  p.flags = (unsigned*)ws;                  // 320 uints used, 512 reserved
  p.Wopt = ws + 512;                        // 2048*832      = 1,703,936 floats
  p.h_buf = p.Wopt + (size_t)NROWS * KTOT;  // 2*64*512      = 65,536 floats
  p.r_buf = p.h_buf + 2 * BB * CDIM;        // 64*64         = 4,096 floats

  hipMemsetAsync(p.flags, 0, 512 * sizeof(unsigned), stream);

  const int total = NROWS * KTOT;
  hipLaunchKernelGGL(transpose_w_kernel, dim3((total + 255) / 256), dim3(256), 0, stream,
                     p.W_ih, p.W_hh, p.Wopt);

  void* kargs[] = { (void*)&p };
  hipLaunchCooperativeKernel((const void*)mann_kernel, dim3(256), dim3(256), kargs, 0, stream);
}

// Round 5
// 24637.340 us; speedup vs baseline: 1.1686x; 1.0070x over previous
//
#include <hip/hip_runtime.h>

#define TT 512
#define BB 64
#define IDIM 256
#define CDIM 512
#define NMEM 128
#define MDIM 64
#define KTOT 832     // (IDIM + M) + CDIM = 320 + 512
#define ODIM 576     // CDIM + M
#define NROWS 2048   // 4*CDIM

struct Params {
  const float* embs; const float* W_ih; const float* W_hh; const float* b_ih; const float* b_hh;
  const float* W_kr; const float* b_kr; const float* w_br; const float* W_kw; const float* b_kw;
  const float* w_bw; const float* W_e; const float* b_e; const float* W_a; const float* b_a;
  const float* h0; const float* c0; const float* r0; const float* mem0;
  float* out;
  unsigned* flags; // [256]: A-flags (phase A done count), [256..320): B-flags
  float* Wopt;   // [2048*832] reordered as [w][k][lr]
  float* h_buf;  // [2][B*CDIM] double buffered (written ONLY via agent atomics)
  float* r_buf;  // [B*M]                      (written ONLY via agent atomics)
};

__device__ __forceinline__ float sigmoidf_(float x) { return 1.0f / (1.0f + __expf(-x)); }
__device__ __forceinline__ float tanhf_(float x) {
  float e = __expf(-2.0f * fabsf(x));
  float t = (1.0f - e) / (1.0f + e);
  return copysignf(t, x);
}
__device__ __forceinline__ float softplusf_(float x) {
  return (x > 20.0f) ? x : log1pf(__expf(x));
}
__device__ __forceinline__ float wred_sum(float v) {
#pragma unroll
  for (int off = 32; off > 0; off >>= 1) v += __shfl_xor(v, off, 64);
  return v;
}
__device__ __forceinline__ float wred_max(float v) {
#pragma unroll
  for (int off = 32; off > 0; off >>= 1) v = fmaxf(v, __shfl_xor(v, off, 64));
  return v;
}
__device__ __forceinline__ unsigned wred_minu(unsigned v) {
#pragma unroll
  for (int off = 32; off > 0; off >>= 1) {
    unsigned o = (unsigned)__shfl_xor((int)v, off, 64);
    v = (o < v) ? o : v;
  }
  return v;
}

__device__ __forceinline__ unsigned flag_ld(const unsigned* f) {
  return __hip_atomic_load(f, __ATOMIC_RELAXED, __HIP_MEMORY_SCOPE_AGENT);
}
// Write-through store to the coherence point (same mechanism as the flag words).
__device__ __forceinline__ void st_wt(float* p, float v) {
  __hip_atomic_store(p, v, __ATOMIC_RELAXED, __HIP_MEMORY_SCOPE_AGENT);
}
// Publish: data was written via st_wt and drained (vmcnt0 + barrier) -> just store flag.
__device__ __forceinline__ void flag_post(unsigned* f, unsigned val) {
  __hip_atomic_store(f, val, __ATOMIC_RELAXED, __HIP_MEMORY_SCOPE_AGENT);
}
__device__ __forceinline__ void drain_vm() {
  asm volatile("s_waitcnt vmcnt(0)" ::: "memory");
}

// Wave-0-only wait: poll A-flags until all >= target, then one acquire fence
// (buffer_inv). Caller must __syncthreads() after.
__device__ __forceinline__ void grid_wait_A(const unsigned* flags, int lane, unsigned target) {
  const unsigned* fA = flags + lane * 4;
  for (;;) {
    unsigned a0 = flag_ld(fA + 0);
    unsigned a1 = flag_ld(fA + 1);
    unsigned a2 = flag_ld(fA + 2);
    unsigned a3 = flag_ld(fA + 3);
    unsigned m = a0 < a1 ? a0 : a1;
    unsigned n = a2 < a3 ? a2 : a3;
    m = m < n ? m : n;
    m = wred_minu(m);
    if (m >= target) break;
    __builtin_amdgcn_s_sleep(1);
  }
  __builtin_amdgcn_fence(__ATOMIC_ACQUIRE, "agent");   // buffer_inv only
}
// Wave-0-only wait on the 64 B-flags, then acquire fence. Caller syncs after.
__device__ __forceinline__ void grid_wait_B(const unsigned* flags, int lane, unsigned target) {
  const unsigned* fB = flags + 256 + lane;
  for (;;) {
    unsigned b = flag_ld(fB);
    b = wred_minu(b);
    if (b >= target) break;
    __builtin_amdgcn_s_sleep(1);
  }
  __builtin_amdgcn_fence(__ATOMIC_ACQUIRE, "agent");   // buffer_inv only
}

// Pre-transpose combined weights into Wopt[(w*832 + k)*8 + lr],
// lr -> global gate row = 512*(lr>>1) + 2*w + (lr&1)
__global__ void __launch_bounds__(256) transpose_w_kernel(const float* __restrict__ W_ih,
                                                          const float* __restrict__ W_hh,
                                                          float* __restrict__ Wopt) {
  int idx = blockIdx.x * 256 + threadIdx.x;
  if (idx >= NROWS * KTOT) return;
  int lr = idx & 7;
  int rem = idx >> 3;          // w*832 + k
  int k = rem % KTOT;
  int w = rem / KTOT;
  int row = 512 * (lr >> 1) + 2 * w + (lr & 1);
  float v = (k < 320) ? W_ih[(size_t)row * 320 + k] : W_hh[(size_t)row * 512 + (k - 320)];
  Wopt[idx] = v;
}

__global__ void __launch_bounds__(256) mann_kernel(Params p) {
  const int w = blockIdx.x;       // 0..255 : owns c-dims {2w, 2w+1}
  const int tid = threadIdx.x;
  const int lane = tid & 63;
  const int q = tid >> 6;         // wave id 0..3

  // phase-A staging (xs aliased with cross-wave reduce buffer)
  __shared__ __align__(16) float xs[64 * 65];          // [kk][b] stride 65 (conflict-free)
  __shared__ __align__(16) float wsa[KTOT * 8];        // resident weights [k][lr]
  __shared__ float bsum[8];
  // phase-B (batch WGs only)
  __shared__ __align__(16) float Mem_s[MDIM][NMEM + 1];  // [m][n] stride 129 (conflict-free)
  __shared__ __align__(16) float hb[CDIM];
  __shared__ float kw_s[MDIM], kr_s[MDIM], e_s[MDIM], a_s[MDIM];
  __shared__ float ww_s[NMEM], wr_s[NMEM];
  __shared__ float sc[8];  // 0:betaw 1:betar 2:|kw| 3:|kr| 4,5:max parts 6,7:sum parts

  // ---------------- init ----------------
  {
    const float4* src = (const float4*)(p.Wopt + (size_t)w * KTOT * 8);
    float4* dst = (float4*)wsa;
    for (int i = tid; i < KTOT * 2; i += 256) dst[i] = src[i];
  }
  if (tid < 8) {
    int row = 512 * (tid >> 1) + 2 * w + (tid & 1);
    bsum[tid] = p.b_ih[row] + p.b_hh[row];
  }
  float c_reg = 0.0f;  // valid for tid<128: cell state for (b=tid&63, j=2w+(tid>>6))
  if (tid < 128) {
    int jj = tid >> 6, b = tid & 63;
    int j = 2 * w + jj;
    c_reg = p.c0[j];
    st_wt(p.h_buf + (size_t)b * CDIM + j, p.h0[j]);  // h_buf[0]
  }
  if (w < BB) {
    for (int idx = tid; idx < NMEM * MDIM; idx += 256) {
      int n = idx >> 6, m = idx & 63;
      Mem_s[m][n] = p.mem0[idx];  // mem0[n][m] -> Mem_s[m][n]
    }
    if (tid < MDIM) st_wt(p.r_buf + w * MDIM + tid, p.r0[tid]);
  }
  drain_vm();
  __syncthreads();
  if (tid == 0) {
    flag_post(&p.flags[w], 1u);
    if (w < BB) flag_post(&p.flags[256 + w], 1u);
  }

  const int kk4 = (tid & 15) * 4;
  const int bb0 = tid >> 4;

#pragma unroll 1
  for (int t = 0; t < TT; ++t) {
    // prefetch chunk 0 (embs: immutable, flag-independent) BEFORE the entry wait
    float4 vbuf[4];
#pragma unroll
    for (int i = 0; i < 4; ++i) {
      const int b = bb0 + 16 * i;
      vbuf[i] = *(const float4*)(p.embs + ((size_t)t * BB + b) * IDIM + kk4);
    }

    // ---- entry: all A(t-1) done -> h(t) readable. (No B condition needed:
    //      chunks 0-3,5-12 touch neither r_buf nor h_write.) ----
    if (tid < 64) grid_wait_A(p.flags, lane, (unsigned)(t + 1));
    __syncthreads();

    const float* h_read = p.h_buf + (size_t)(t & 1) * (BB * CDIM);
    float* h_write = p.h_buf + (size_t)((t + 1) & 1) * (BB * CDIM);

    // ---------------- Phase A part 1: chunks 0..3 (emb), 5..12 (h) ----------------
    float acc[8];
#pragma unroll
    for (int i = 0; i < 8; ++i) acc[i] = 0.0f;

    int cur = 0;
#pragma unroll 1
    for (int ci = 0; ci < 12; ++ci) {
      // store prefetched x chunk `cur` to LDS
#pragma unroll
      for (int i = 0; i < 4; ++i) {
        const int b = bb0 + 16 * i;
        xs[(kk4 + 0) * 65 + b] = vbuf[i].x;
        xs[(kk4 + 1) * 65 + b] = vbuf[i].y;
        xs[(kk4 + 2) * 65 + b] = vbuf[i].z;
        xs[(kk4 + 3) * 65 + b] = vbuf[i].w;
      }
      __syncthreads();

      const int nxt = (cur == 3) ? 5 : cur + 1;  // skip chunk 4 (r) -- deferred
      // issue next chunk's global loads (overlap with compute below)
      if (ci < 11) {
        const int k = nxt * 64 + kk4;
#pragma unroll
        for (int i = 0; i < 4; ++i) {
          const int b = bb0 + 16 * i;
          if (nxt < 4) vbuf[i] = *(const float4*)(p.embs + ((size_t)t * BB + b) * IDIM + k);
          else         vbuf[i] = *(const float4*)(h_read + (size_t)b * CDIM + (k - 320));
        }
      }

      // wave q computes kk in [16q, 16q+16) for all 8 rows (K-split across waves)
      const int kkb = 16 * q;
#pragma unroll
      for (int kki = 0; kki < 16; ++kki) {
        const int kk = kkb + kki;
        const float xv = xs[kk * 65 + lane];
        const float4 w0 = *(const float4*)&wsa[(cur * 64 + kk) * 8];
        const float4 w1 = *(const float4*)&wsa[(cur * 64 + kk) * 8 + 4];
        acc[0] = fmaf(xv, w0.x, acc[0]);
        acc[1] = fmaf(xv, w0.y, acc[1]);
        acc[2] = fmaf(xv, w0.z, acc[2]);
        acc[3] = fmaf(xv, w0.w, acc[3]);
        acc[4] = fmaf(xv, w1.x, acc[4]);
        acc[5] = fmaf(xv, w1.y, acc[5]);
        acc[6] = fmaf(xv, w1.z, acc[6]);
        acc[7] = fmaf(xv, w1.w, acc[7]);
      }
      __syncthreads();
      cur = nxt;
    }

    // ---- deferred wait: B(t-1) done -> r(t) readable; h_write overwrite safe ----
    if (tid < 64) grid_wait_B(p.flags, lane, (unsigned)(t + 1));
    __syncthreads();

    // ---------------- Phase A part 2: chunk 4 (r) ----------------
    {
#pragma unroll
      for (int i = 0; i < 4; ++i) {
        const int b = bb0 + 16 * i;
        vbuf[i] = *(const float4*)(p.r_buf + b * MDIM + kk4);
      }
#pragma unroll
      for (int i = 0; i < 4; ++i) {
        const int b = bb0 + 16 * i;
        xs[(kk4 + 0) * 65 + b] = vbuf[i].x;
        xs[(kk4 + 1) * 65 + b] = vbuf[i].y;
        xs[(kk4 + 2) * 65 + b] = vbuf[i].z;
        xs[(kk4 + 3) * 65 + b] = vbuf[i].w;
      }
      __syncthreads();
      const int kkb = 16 * q;
#pragma unroll
      for (int kki = 0; kki < 16; ++kki) {
        const int kk = kkb + kki;
        const float xv = xs[kk * 65 + lane];
        const float4 w0 = *(const float4*)&wsa[(4 * 64 + kk) * 8];
        const float4 w1 = *(const float4*)&wsa[(4 * 64 + kk) * 8 + 4];
        acc[0] = fmaf(xv, w0.x, acc[0]);
        acc[1] = fmaf(xv, w0.y, acc[1]);
        acc[2] = fmaf(xv, w0.z, acc[2]);
        acc[3] = fmaf(xv, w0.w, acc[3]);
        acc[4] = fmaf(xv, w1.x, acc[4]);
        acc[5] = fmaf(xv, w1.y, acc[5]);
        acc[6] = fmaf(xv, w1.z, acc[6]);
        acc[7] = fmaf(xv, w1.w, acc[7]);
      }
      __syncthreads();
    }

    // cross-wave K reduction (reuse xs region)
    {
      float* red = xs;  // [q][lr][b] = [4][8][64]
#pragma unroll
      for (int lr = 0; lr < 8; ++lr) red[(q * 8 + lr) * 64 + lane] = acc[lr];
      __syncthreads();
      if (tid < 128) {
        const int jj = tid >> 6, b = tid & 63;
        float g[4];
#pragma unroll
        for (int gate = 0; gate < 4; ++gate) {
          const int lr = gate * 2 + jj;
          float s = bsum[lr];
#pragma unroll
          for (int qq = 0; qq < 4; ++qq) s += red[(qq * 8 + lr) * 64 + b];
          g[gate] = s;
        }
        const float iv = sigmoidf_(g[0]);
        const float fv = sigmoidf_(g[1]);
        const float gv = tanhf_(g[2]);
        const float ov = sigmoidf_(g[3]);
        c_reg = fv * c_reg + iv * gv;
        const float hv = ov * tanhf_(c_reg);
        st_wt(h_write + (size_t)b * CDIM + 2 * w + jj, hv);
      }
    }
    // ---- publish phase A: write-through data drained, then private flag ----
    drain_vm();
    __syncthreads();
    if (tid == 0) flag_post(&p.flags[w], (unsigned)(t + 2));

    // ---------------- Phase B: heads + addressing + memory (batch WGs) ----------------
    if (w < BB) {
      // wait for ALL producers' h(t) slices
      if (tid < 64) grid_wait_A(p.flags, lane, (unsigned)(t + 2));
      __syncthreads();

      const int b = w;
      hb[tid] = h_write[(size_t)b * CDIM + tid];
      hb[tid + 256] = h_write[(size_t)b * CDIM + tid + 256];
      __syncthreads();
      // head GEMVs: [0,64):kw  [64,128):e  [128,192):kr  192:betaw 193:betar
      if (tid < 194) {
        const float* Wrow;
        if (tid < 64)        Wrow = p.W_kw + (size_t)tid * CDIM;
        else if (tid < 128)  Wrow = p.W_e + (size_t)(tid - 64) * CDIM;
        else if (tid < 192)  Wrow = p.W_kr + (size_t)(tid - 128) * CDIM;
        else if (tid == 192) Wrow = p.w_bw;
        else                 Wrow = p.w_br;
        float s = 0.0f;
#pragma unroll 4
        for (int k = 0; k < CDIM; k += 4) {
          const float4 wv = *(const float4*)(Wrow + k);
          s = fmaf(wv.x, hb[k], s);
          s = fmaf(wv.y, hb[k + 1], s);
          s = fmaf(wv.z, hb[k + 2], s);
          s = fmaf(wv.w, hb[k + 3], s);
        }
        if (tid < 64)       kw_s[tid] = tanhf_(s + p.b_kw[tid]);
        else if (tid < 128) e_s[tid - 64] = sigmoidf_(s + p.b_e[tid - 64]);
        else if (tid < 192) kr_s[tid - 128] = tanhf_(s + p.b_kr[tid - 128]);
        else                sc[tid - 192] = softplusf_(s);
      }
      // a = tanh(emb @ W_a^T + b_a)
      if (tid < 64) {
        const float* Wrow = p.W_a + (size_t)tid * IDIM;
        const float* eb = p.embs + ((size_t)t * BB + b) * IDIM;
        float s = p.b_a[tid];
#pragma unroll 4
        for (int k = 0; k < IDIM; k += 4) {
          const float4 wv = *(const float4*)(Wrow + k);
          const float4 ev = *(const float4*)(eb + k);
          s = fmaf(wv.x, ev.x, s);
          s = fmaf(wv.y, ev.y, s);
          s = fmaf(wv.z, ev.z, s);
          s = fmaf(wv.w, ev.w, s);
        }
        a_s[tid] = tanhf_(s);
      }
      __syncthreads();
      // key norms: wave0 -> |kw|, wave1 -> |kr|
      if (tid < 128) {
        const float v = (q == 0) ? kw_s[lane] : kr_s[lane];
        const float ss = wred_sum(v * v);
        if (lane == 0) sc[2 + q] = sqrtf(ss);
      }
      __syncthreads();
      // ---- write addressing (on old Mem) ----
      {
        float logit = 0.0f, ex = 0.0f;
        const float beta = sc[0], keyn = sc[2];
        if (tid < 128) {
          float sim = 0.0f, nrm = 0.0f;
#pragma unroll 8
          for (int m = 0; m < MDIM; ++m) {
            const float mv = Mem_s[m][tid];
            sim = fmaf(mv, kw_s[m], sim);
            nrm = fmaf(mv, mv, nrm);
          }
          logit = beta * sim / (sqrtf(nrm) * keyn + 1e-8f);
          const float mx = wred_max(logit);
          if (lane == 0) sc[4 + q] = mx;
        }
        __syncthreads();
        if (tid < 128) {
          ex = __expf(logit - fmaxf(sc[4], sc[5]));
          const float sm = wred_sum(ex);
          if (lane == 0) sc[6 + q] = sm;
        }
        __syncthreads();
        if (tid < 128) ww_s[tid] = ex / (sc[6] + sc[7]);
        __syncthreads();
      }
      // ---- memory write (erase/add) ----
      for (int idx = tid; idx < NMEM * MDIM; idx += 256) {
        const int m = idx >> 7, n = idx & 127;
        const float mv = Mem_s[m][n];
        Mem_s[m][n] = mv * (1.0f - ww_s[n] * e_s[m]) + ww_s[n] * a_s[m];
      }
      __syncthreads();
      // ---- read addressing (on new Mem) ----
      {
        float logit = 0.0f, ex = 0.0f;
        const float beta = sc[1], keyn = sc[3];
        if (tid < 128) {
          float sim = 0.0f, nrm = 0.0f;
#pragma unroll 8
          for (int m = 0; m < MDIM; ++m) {
            const float mv = Mem_s[m][tid];
            sim = fmaf(mv, kr_s[m], sim);
            nrm = fmaf(mv, mv, nrm);
          }
          logit = beta * sim / (sqrtf(nrm) * keyn + 1e-8f);
          const float mx = wred_max(logit);
          if (lane == 0) sc[4 + q] = mx;
        }
        __syncthreads();
        if (tid < 128) {
          ex = __expf(logit - fmaxf(sc[4], sc[5]));
          const float sm = wred_sum(ex);
          if (lane == 0) sc[6 + q] = sm;
        }
        __syncthreads();
        if (tid < 128) wr_s[tid] = ex / (sc[6] + sc[7]);
        __syncthreads();
      }
      // ---- read vector + outputs ----
      if (tid < 64) {
        float rv = 0.0f;
#pragma unroll 8
        for (int n = 0; n < NMEM; ++n) rv = fmaf(wr_s[n], Mem_s[tid][n], rv);
        st_wt(p.r_buf + b * MDIM + tid, rv);
        p.out[((size_t)t * BB + b) * ODIM + 512 + tid] = rv;
      }
      p.out[((size_t)t * BB + b) * ODIM + tid] = hb[tid];
      p.out[((size_t)t * BB + b) * ODIM + 256 + tid] = hb[tid + 256];
      // ---- publish phase B (write-through drained, then private flag) ----
      drain_vm();
      __syncthreads();
      if (tid == 0) flag_post(&p.flags[256 + w], (unsigned)(t + 2));
    }
  }
}

extern "C" void kernel_launch(void* const* d_in, const int* in_sizes, int n_in,
                              void* d_out, int out_size, void* d_ws, size_t ws_size,
                              hipStream_t stream) {
  (void)in_sizes; (void)n_in; (void)out_size; (void)ws_size;
  Params p;
  p.embs = (const float*)d_in[0];
  p.W_ih = (const float*)d_in[1];
  p.W_hh = (const float*)d_in[2];
  p.b_ih = (const float*)d_in[3];
  p.b_hh = (const float*)d_in[4];
  p.W_kr = (const float*)d_in[5];
  p.b_kr = (const float*)d_in[6];
  p.w_br = (const float*)d_in[7];
  p.W_kw = (const float*)d_in[8];
  p.b_kw = (const float*)d_in[9];
  p.w_bw = (const float*)d_in[10];
  p.W_e  = (const float*)d_in[11];
  p.b_e  = (const float*)d_in[12];
  p.W_a  = (const float*)d_in[13];
  p.b_a  = (const float*)d_in[14];
  p.h0   = (const float*)d_in[15];
  p.c0   = (const float*)d_in[16];
  p.r0   = (const float*)d_in[17];
  p.mem0 = (const float*)d_in[18];
  p.out = (float*)d_out;

  float* ws = (float*)d_ws;
  p.flags = (unsigned*)ws;                  // 320 uints used, 512 reserved
  p.Wopt = ws + 512;                        // 2048*832      = 1,703,936 floats
  p.h_buf = p.Wopt + (size_t)NROWS * KTOT;  // 2*64*512      = 65,536 floats
  p.r_buf = p.h_buf + 2 * BB * CDIM;        // 64*64         = 4,096 floats

  hipMemsetAsync(p.flags, 0, 512 * sizeof(unsigned), stream);

  const int total = NROWS * KTOT;
  hipLaunchKernelGGL(transpose_w_kernel, dim3((total + 255) / 256), dim3(256), 0, stream,
                     p.W_ih, p.W_hh, p.Wopt);

  void* kargs[] = { (void*)&p };
  hipLaunchCooperativeKernel((const void*)mann_kernel, dim3(256), dim3(256), kargs, 0, stream);
}

// Round 6
// 21082.185 us; speedup vs baseline: 1.3657x; 1.1686x over previous
//
#include <hip/hip_runtime.h>

#define TT 512
#define BB 64
#define IDIM 256
#define CDIM 512
#define NMEM 128
#define MDIM 64
#define KTOT 832     // (IDIM + M) + CDIM = 320 + 512
#define ODIM 576     // CDIM + M
#define NROWS 2048   // 4*CDIM

struct Params {
  const float* embs; const float* W_ih; const float* W_hh; const float* b_ih; const float* b_hh;
  const float* W_kr; const float* b_kr; const float* w_br; const float* W_kw; const float* b_kw;
  const float* w_bw; const float* W_e; const float* b_e; const float* W_a; const float* b_a;
  const float* h0; const float* c0; const float* r0; const float* mem0;
  float* out;
  unsigned* flags; // [0..256): A-write flags, [256..320): B flags, [320..576): A-read flags
  float* Wopt;   // [2048*832] reordered as [w][k][lr]
  float* h_buf;  // [2][B*CDIM] double buffered (st_wt writes, ld2_wt reads)
  float* r_buf;  // [B*M]                      (st_wt writes, ld2_wt reads)
};

__device__ __forceinline__ float sigmoidf_(float x) { return 1.0f / (1.0f + __expf(-x)); }
__device__ __forceinline__ float tanhf_(float x) {
  float e = __expf(-2.0f * fabsf(x));
  float t = (1.0f - e) / (1.0f + e);
  return copysignf(t, x);
}
__device__ __forceinline__ float softplusf_(float x) {
  return (x > 20.0f) ? x : log1pf(__expf(x));
}
__device__ __forceinline__ float wred_sum(float v) {
#pragma unroll
  for (int off = 32; off > 0; off >>= 1) v += __shfl_xor(v, off, 64);
  return v;
}
__device__ __forceinline__ float wred_max(float v) {
#pragma unroll
  for (int off = 32; off > 0; off >>= 1) v = fmaxf(v, __shfl_xor(v, off, 64));
  return v;
}
__device__ __forceinline__ unsigned wred_minu(unsigned v) {
#pragma unroll
  for (int off = 32; off > 0; off >>= 1) {
    unsigned o = (unsigned)__shfl_xor((int)v, off, 64);
    v = (o < v) ? o : v;
  }
  return v;
}

__device__ __forceinline__ unsigned flag_ld(const unsigned* f) {
  return __hip_atomic_load(f, __ATOMIC_RELAXED, __HIP_MEMORY_SCOPE_AGENT);
}
// Write-through store to the coherence point (same mechanism as the flag words).
__device__ __forceinline__ void st_wt(float* p, float v) {
  __hip_atomic_store(p, v, __ATOMIC_RELAXED, __HIP_MEMORY_SCOPE_AGENT);
}
__device__ __forceinline__ void flag_post(unsigned* f, unsigned val) {
  __hip_atomic_store(f, val, __ATOMIC_RELAXED, __HIP_MEMORY_SCOPE_AGENT);
}
__device__ __forceinline__ void drain_vm() {
  asm volatile("s_waitcnt vmcnt(0)" ::: "memory");
}
// Agent-coherent 8-byte data load (bypasses stale L2; same path the flags use).
__device__ __forceinline__ float2 ld2_wt(const float* p) {
  unsigned long long v = __hip_atomic_load((const unsigned long long*)p,
                                           __ATOMIC_RELAXED, __HIP_MEMORY_SCOPE_AGENT);
  float2 r;
  r.x = __uint_as_float((unsigned)(v & 0xFFFFFFFFull));
  r.y = __uint_as_float((unsigned)(v >> 32));
  return r;
}

// Poll 32 flags [base, base+32) until all >= target. Called by ALL waves
// (each wave gates its own subsequent loads). Compiler barrier at exit;
// no HW fence needed (gated data is read via ld2_wt).
__device__ __forceinline__ void wait_group32(const unsigned* base, int lane, unsigned target) {
  for (;;) {
    unsigned v = (lane < 32) ? flag_ld(base + lane) : 0xFFFFFFFFu;
    v = wred_minu(v);
    if (v >= target) break;
    __builtin_amdgcn_s_sleep(1);
  }
  asm volatile("" ::: "memory");
}
// Poll 256 flags (4 per lane), single wave. Caller must __syncthreads() after.
__device__ __forceinline__ void wait_all256(const unsigned* f, int lane, unsigned target) {
  const unsigned* fp = f + lane * 4;
  for (;;) {
    unsigned a0 = flag_ld(fp + 0);
    unsigned a1 = flag_ld(fp + 1);
    unsigned a2 = flag_ld(fp + 2);
    unsigned a3 = flag_ld(fp + 3);
    unsigned m = a0 < a1 ? a0 : a1;
    unsigned n = a2 < a3 ? a2 : a3;
    m = m < n ? m : n;
    m = wred_minu(m);
    if (m >= target) break;
    __builtin_amdgcn_s_sleep(1);
  }
  asm volatile("" ::: "memory");
}
// Poll 64 flags (1 per lane). Called by all waves.
__device__ __forceinline__ void wait_all64(const unsigned* f, int lane, unsigned target) {
  const unsigned* fp = f + lane;
  for (;;) {
    unsigned b = flag_ld(fp);
    b = wred_minu(b);
    if (b >= target) break;
    __builtin_amdgcn_s_sleep(1);
  }
  asm volatile("" ::: "memory");
}

// Pre-transpose combined weights into Wopt[(w*832 + k)*8 + lr],
// lr -> global gate row = 512*(lr>>1) + 2*w + (lr&1)
__global__ void __launch_bounds__(256) transpose_w_kernel(const float* __restrict__ W_ih,
                                                          const float* __restrict__ W_hh,
                                                          float* __restrict__ Wopt) {
  int idx = blockIdx.x * 256 + threadIdx.x;
  if (idx >= NROWS * KTOT) return;
  int lr = idx & 7;
  int rem = idx >> 3;          // w*832 + k
  int k = rem % KTOT;
  int w = rem / KTOT;
  int row = 512 * (lr >> 1) + 2 * w + (lr & 1);
  float v = (k < 320) ? W_ih[(size_t)row * 320 + k] : W_hh[(size_t)row * 512 + (k - 320)];
  Wopt[idx] = v;
}

__global__ void __launch_bounds__(256) mann_kernel(Params p) {
  const int w = blockIdx.x;       // 0..255 : owns c-dims {2w, 2w+1}
  const int tid = threadIdx.x;
  const int lane = tid & 63;
  const int q = tid >> 6;         // wave id 0..3

  unsigned* Aw = p.flags;         // 256 A-write flags
  unsigned* Bf = p.flags + 256;   // 64 B flags
  unsigned* Ar = p.flags + 320;   // 256 A-read flags

  // phase-A staging (xs aliased with cross-wave reduce buffer)
  __shared__ __align__(16) float xs[64 * 65];          // [kk][b] stride 65 (conflict-free)
  __shared__ __align__(16) float wsa[KTOT * 8];        // resident weights [k][lr]
  __shared__ float bsum[8];
  // phase-B (batch WGs only)
  __shared__ __align__(16) float Mem_s[MDIM][NMEM + 1];  // [m][n] stride 129 (conflict-free)
  __shared__ __align__(16) float hb[CDIM];
  __shared__ float kw_s[MDIM], kr_s[MDIM], e_s[MDIM], a_s[MDIM];
  __shared__ float ww_s[NMEM], wr_s[NMEM];
  __shared__ float sc[8];  // 0:betaw 1:betar 2:|kw| 3:|kr| 4,5:max parts 6,7:sum parts

  // ---------------- init ----------------
  {
    const float4* src = (const float4*)(p.Wopt + (size_t)w * KTOT * 8);
    float4* dst = (float4*)wsa;
    for (int i = tid; i < KTOT * 2; i += 256) dst[i] = src[i];
  }
  if (tid < 8) {
    int row = 512 * (tid >> 1) + 2 * w + (tid & 1);
    bsum[tid] = p.b_ih[row] + p.b_hh[row];
  }
  float c_reg = 0.0f;  // valid for tid<128: cell state for (b=tid&63, j=2w+(tid>>6))
  if (tid < 128) {
    int jj = tid >> 6, b = tid & 63;
    int j = 2 * w + jj;
    c_reg = p.c0[j];
    st_wt(p.h_buf + (size_t)b * CDIM + j, p.h0[j]);  // h_buf[0]
  }
  if (w < BB) {
    for (int idx = tid; idx < NMEM * MDIM; idx += 256) {
      int n = idx >> 6, m = idx & 63;
      Mem_s[m][n] = p.mem0[idx];  // mem0[n][m] -> Mem_s[m][n]
    }
    if (tid < MDIM) st_wt(p.r_buf + w * MDIM + tid, p.r0[tid]);
  }
  drain_vm();
  __syncthreads();
  if (tid == 0) {
    flag_post(&Aw[w], 1u);
    flag_post(&Ar[w], 1u);
    if (w < BB) flag_post(&Bf[w], 1u);
  }

  const int kk4 = (tid & 15) * 4;
  const int bb0 = tid >> 4;

#pragma unroll 1
  for (int t = 0; t < TT; ++t) {
    // prefetch chunk 0 (embs: immutable) — no wait needed at step entry
    float4 vbuf[4];
#pragma unroll
    for (int i = 0; i < 4; ++i) {
      const int b = bb0 + 16 * i;
      vbuf[i] = *(const float4*)(p.embs + ((size_t)t * BB + b) * IDIM + kk4);
    }

    const float* h_read = p.h_buf + (size_t)(t & 1) * (BB * CDIM);
    float* h_write = p.h_buf + (size_t)((t + 1) & 1) * (BB * CDIM);

    float acc[8];
#pragma unroll
    for (int i = 0; i < 8; ++i) acc[i] = 0.0f;

    // ---------------- Phase A part 1: chunks 0..3 (emb), 5..12 (h) ----------------
    int cur = 0;
#pragma unroll 1
    for (int ci = 0; ci < 12; ++ci) {
      // store prefetched x chunk `cur` to LDS
#pragma unroll
      for (int i = 0; i < 4; ++i) {
        const int b = bb0 + 16 * i;
        xs[(kk4 + 0) * 65 + b] = vbuf[i].x;
        xs[(kk4 + 1) * 65 + b] = vbuf[i].y;
        xs[(kk4 + 2) * 65 + b] = vbuf[i].z;
        xs[(kk4 + 3) * 65 + b] = vbuf[i].w;
      }
      __syncthreads();

      const int nxt = (cur == 3) ? 5 : cur + 1;  // skip chunk 4 (r) -- deferred
      if (ci < 11) {
        if (nxt >= 5) {
          // h-chunk nxt needs only the 32 producers of its h-dims
          wait_group32(Aw + (nxt - 5) * 32, lane, (unsigned)(t + 1));
          const int k = nxt * 64 + kk4 - 320;
#pragma unroll
          for (int i = 0; i < 4; ++i) {
            const int b = bb0 + 16 * i;
            const float* src = h_read + (size_t)b * CDIM + k;
            const float2 lo = ld2_wt(src);
            const float2 hi = ld2_wt(src + 2);
            vbuf[i].x = lo.x; vbuf[i].y = lo.y; vbuf[i].z = hi.x; vbuf[i].w = hi.y;
          }
        } else {
          const int k = nxt * 64 + kk4;
#pragma unroll
          for (int i = 0; i < 4; ++i) {
            const int b = bb0 + 16 * i;
            vbuf[i] = *(const float4*)(p.embs + ((size_t)t * BB + b) * IDIM + k);
          }
        }
      }

      // wave q computes kk in [16q, 16q+16) for all 8 rows (K-split across waves)
      const int kkb = 16 * q;
#pragma unroll
      for (int kki = 0; kki < 16; ++kki) {
        const int kk = kkb + kki;
        const float xv = xs[kk * 65 + lane];
        const float4 w0 = *(const float4*)&wsa[(cur * 64 + kk) * 8];
        const float4 w1 = *(const float4*)&wsa[(cur * 64 + kk) * 8 + 4];
        acc[0] = fmaf(xv, w0.x, acc[0]);
        acc[1] = fmaf(xv, w0.y, acc[1]);
        acc[2] = fmaf(xv, w0.z, acc[2]);
        acc[3] = fmaf(xv, w0.w, acc[3]);
        acc[4] = fmaf(xv, w1.x, acc[4]);
        acc[5] = fmaf(xv, w1.y, acc[5]);
        acc[6] = fmaf(xv, w1.z, acc[6]);
        acc[7] = fmaf(xv, w1.w, acc[7]);
      }
      __syncthreads();
      cur = nxt;
    }

    // publish A-read: this block is done reading h_read for step t
    if (tid == 0) flag_post(&Ar[w], (unsigned)(t + 2));

    // ---- r chunk: needs B(t-1) done -> r(t) readable ----
    wait_all64(Bf, lane, (unsigned)(t + 1));
    {
#pragma unroll
      for (int i = 0; i < 4; ++i) {
        const int b = bb0 + 16 * i;
        const float* src = p.r_buf + b * MDIM + kk4;
        const float2 lo = ld2_wt(src);
        const float2 hi = ld2_wt(src + 2);
        vbuf[i].x = lo.x; vbuf[i].y = lo.y; vbuf[i].z = hi.x; vbuf[i].w = hi.y;
      }
#pragma unroll
      for (int i = 0; i < 4; ++i) {
        const int b = bb0 + 16 * i;
        xs[(kk4 + 0) * 65 + b] = vbuf[i].x;
        xs[(kk4 + 1) * 65 + b] = vbuf[i].y;
        xs[(kk4 + 2) * 65 + b] = vbuf[i].z;
        xs[(kk4 + 3) * 65 + b] = vbuf[i].w;
      }
      __syncthreads();
      const int kkb = 16 * q;
#pragma unroll
      for (int kki = 0; kki < 16; ++kki) {
        const int kk = kkb + kki;
        const float xv = xs[kk * 65 + lane];
        const float4 w0 = *(const float4*)&wsa[(4 * 64 + kk) * 8];
        const float4 w1 = *(const float4*)&wsa[(4 * 64 + kk) * 8 + 4];
        acc[0] = fmaf(xv, w0.x, acc[0]);
        acc[1] = fmaf(xv, w0.y, acc[1]);
        acc[2] = fmaf(xv, w0.z, acc[2]);
        acc[3] = fmaf(xv, w0.w, acc[3]);
        acc[4] = fmaf(xv, w1.x, acc[4]);
        acc[5] = fmaf(xv, w1.y, acc[5]);
        acc[6] = fmaf(xv, w1.z, acc[6]);
        acc[7] = fmaf(xv, w1.w, acc[7]);
      }
      __syncthreads();
    }

    // cross-wave K reduction; WAR wait (all blocks done reading old h_write content)
    {
      float* red = xs;  // [q][lr][b] = [4][8][64]
#pragma unroll
      for (int lr = 0; lr < 8; ++lr) red[(q * 8 + lr) * 64 + lane] = acc[lr];
      __syncthreads();
      if (tid < 64) wait_all256(Ar, lane, (unsigned)(t + 1));
      __syncthreads();
      if (tid < 128) {
        const int jj = tid >> 6, b = tid & 63;
        float g[4];
#pragma unroll
        for (int gate = 0; gate < 4; ++gate) {
          const int lr = gate * 2 + jj;
          float s = bsum[lr];
#pragma unroll
          for (int qq = 0; qq < 4; ++qq) s += red[(qq * 8 + lr) * 64 + b];
          g[gate] = s;
        }
        const float iv = sigmoidf_(g[0]);
        const float fv = sigmoidf_(g[1]);
        const float gv = tanhf_(g[2]);
        const float ov = sigmoidf_(g[3]);
        c_reg = fv * c_reg + iv * gv;
        const float hv = ov * tanhf_(c_reg);
        st_wt(h_write + (size_t)b * CDIM + 2 * w + jj, hv);
      }
    }
    // publish A-write: write-through data drained, then private flag
    drain_vm();
    __syncthreads();
    if (tid == 0) flag_post(&Aw[w], (unsigned)(t + 2));

    // ---------------- Phase B: heads + addressing + memory (batch WGs) ----------------
    if (w < BB) {
      const int b = w;
      // a = tanh(emb @ W_a^T + b_a): immutable inputs
      if (tid < 64) {
        const float* Wrow = p.W_a + (size_t)tid * IDIM;
        const float* eb = p.embs + ((size_t)t * BB + b) * IDIM;
        float s = p.b_a[tid];
#pragma unroll 4
        for (int k = 0; k < IDIM; k += 4) {
          const float4 wv = *(const float4*)(Wrow + k);
          const float4 ev = *(const float4*)(eb + k);
          s = fmaf(wv.x, ev.x, s);
          s = fmaf(wv.y, ev.y, s);
          s = fmaf(wv.z, ev.z, s);
          s = fmaf(wv.w, ev.w, s);
        }
        a_s[tid] = tanhf_(s);
      }
      // wait for ALL producers' h(t) slices
      if (tid < 64) wait_all256(Aw, lane, (unsigned)(t + 2));
      __syncthreads();

      // stage h(t) for this batch (agent-coherent 8B loads)
      {
        const float2 hv = ld2_wt(h_write + (size_t)b * CDIM + tid * 2);
        hb[tid * 2] = hv.x;
        hb[tid * 2 + 1] = hv.y;
      }
      __syncthreads();
      // head GEMVs: [0,64):kw  [64,128):e  [128,192):kr  192:betaw 193:betar
      // (weights stay L2-warm now: no buffer_inv anywhere)
      if (tid < 194) {
        const float* Wrow;
        if (tid < 64)        Wrow = p.W_kw + (size_t)tid * CDIM;
        else if (tid < 128)  Wrow = p.W_e + (size_t)(tid - 64) * CDIM;
        else if (tid < 192)  Wrow = p.W_kr + (size_t)(tid - 128) * CDIM;
        else if (tid == 192) Wrow = p.w_bw;
        else                 Wrow = p.w_br;
        float s = 0.0f;
#pragma unroll 4
        for (int k = 0; k < CDIM; k += 4) {
          const float4 wv = *(const float4*)(Wrow + k);
          s = fmaf(wv.x, hb[k], s);
          s = fmaf(wv.y, hb[k + 1], s);
          s = fmaf(wv.z, hb[k + 2], s);
          s = fmaf(wv.w, hb[k + 3], s);
        }
        if (tid < 64)       kw_s[tid] = tanhf_(s + p.b_kw[tid]);
        else if (tid < 128) e_s[tid - 64] = sigmoidf_(s + p.b_e[tid - 64]);
        else if (tid < 192) kr_s[tid - 128] = tanhf_(s + p.b_kr[tid - 128]);
        else                sc[tid - 192] = softplusf_(s);
      }
      __syncthreads();
      // key norms: wave0 -> |kw|, wave1 -> |kr|
      if (tid < 128) {
        const float v = (q == 0) ? kw_s[lane] : kr_s[lane];
        const float ss = wred_sum(v * v);
        if (lane == 0) sc[2 + q] = sqrtf(ss);
      }
      __syncthreads();
      // ---- write addressing (on old Mem) ----
      {
        float logit = 0.0f, ex = 0.0f;
        const float beta = sc[0], keyn = sc[2];
        if (tid < 128) {
          float sim = 0.0f, nrm = 0.0f;
#pragma unroll 8
          for (int m = 0; m < MDIM; ++m) {
            const float mv = Mem_s[m][tid];
            sim = fmaf(mv, kw_s[m], sim);
            nrm = fmaf(mv, mv, nrm);
          }
          logit = beta * sim / (sqrtf(nrm) * keyn + 1e-8f);
          const float mx = wred_max(logit);
          if (lane == 0) sc[4 + q] = mx;
        }
        __syncthreads();
        if (tid < 128) {
          ex = __expf(logit - fmaxf(sc[4], sc[5]));
          const float sm = wred_sum(ex);
          if (lane == 0) sc[6 + q] = sm;
        }
        __syncthreads();
        if (tid < 128) ww_s[tid] = ex / (sc[6] + sc[7]);
        __syncthreads();
      }
      // ---- memory write (erase/add) ----
      for (int idx = tid; idx < NMEM * MDIM; idx += 256) {
        const int m = idx >> 7, n = idx & 127;
        const float mv = Mem_s[m][n];
        Mem_s[m][n] = mv * (1.0f - ww_s[n] * e_s[m]) + ww_s[n] * a_s[m];
      }
      __syncthreads();
      // ---- read addressing (on new Mem) ----
      {
        float logit = 0.0f, ex = 0.0f;
        const float beta = sc[1], keyn = sc[3];
        if (tid < 128) {
          float sim = 0.0f, nrm = 0.0f;
#pragma unroll 8
          for (int m = 0; m < MDIM; ++m) {
            const float mv = Mem_s[m][tid];
            sim = fmaf(mv, kr_s[m], sim);
            nrm = fmaf(mv, mv, nrm);
          }
          logit = beta * sim / (sqrtf(nrm) * keyn + 1e-8f);
          const float mx = wred_max(logit);
          if (lane == 0) sc[4 + q] = mx;
        }
        __syncthreads();
        if (tid < 128) {
          ex = __expf(logit - fmaxf(sc[4], sc[5]));
          const float sm = wred_sum(ex);
          if (lane == 0) sc[6 + q] = sm;
        }
        __syncthreads();
        if (tid < 128) wr_s[tid] = ex / (sc[6] + sc[7]);
        __syncthreads();
      }
      // ---- read vector + outputs ----
      if (tid < 64) {
        float rv = 0.0f;
#pragma unroll 8
        for (int n = 0; n < NMEM; ++n) rv = fmaf(wr_s[n], Mem_s[tid][n], rv);
        st_wt(p.r_buf + b * MDIM + tid, rv);
        p.out[((size_t)t * BB + b) * ODIM + 512 + tid] = rv;
      }
      p.out[((size_t)t * BB + b) * ODIM + tid] = hb[tid];
      p.out[((size_t)t * BB + b) * ODIM + 256 + tid] = hb[tid + 256];
      // publish B (write-through drained, then private flag)
      drain_vm();
      __syncthreads();
      if (tid == 0) flag_post(&Bf[w], (unsigned)(t + 2));
    }
  }
}

extern "C" void kernel_launch(void* const* d_in, const int* in_sizes, int n_in,
                              void* d_out, int out_size, void* d_ws, size_t ws_size,
                              hipStream_t stream) {
  (void)in_sizes; (void)n_in; (void)out_size; (void)ws_size;
  Params p;
  p.embs = (const float*)d_in[0];
  p.W_ih = (const float*)d_in[1];
  p.W_hh = (const float*)d_in[2];
  p.b_ih = (const float*)d_in[3];
  p.b_hh = (const float*)d_in[4];
  p.W_kr = (const float*)d_in[5];
  p.b_kr = (const float*)d_in[6];
  p.w_br = (const float*)d_in[7];
  p.W_kw = (const float*)d_in[8];
  p.b_kw = (const float*)d_in[9];
  p.w_bw = (const float*)d_in[10];
  p.W_e  = (const float*)d_in[11];
  p.b_e  = (const float*)d_in[12];
  p.W_a  = (const float*)d_in[13];
  p.b_a  = (const float*)d_in[14];
  p.h0   = (const float*)d_in[15];
  p.c0   = (const float*)d_in[16];
  p.r0   = (const float*)d_in[17];
  p.mem0 = (const float*)d_in[18];
  p.out = (float*)d_out;

  float* ws = (float*)d_ws;
  p.flags = (unsigned*)ws;                  // 576 uints used, 1024 reserved
  p.Wopt = ws + 1024;                       // 2048*832      = 1,703,936 floats
  p.h_buf = p.Wopt + (size_t)NROWS * KTOT;  // 2*64*512      = 65,536 floats
  p.r_buf = p.h_buf + 2 * BB * CDIM;        // 64*64         = 4,096 floats

  hipMemsetAsync(p.flags, 0, 1024 * sizeof(unsigned), stream);

  const int total = NROWS * KTOT;
  hipLaunchKernelGGL(transpose_w_kernel, dim3((total + 255) / 256), dim3(256), 0, stream,
                     p.W_ih, p.W_hh, p.Wopt);

  void* kargs[] = { (void*)&p };
  hipLaunchCooperativeKernel((const void*)mann_kernel, dim3(256), dim3(256), kargs, 0, stream);
}

// Round 8
// 16809.459 us; speedup vs baseline: 1.7128x; 1.2542x over previous
//
#include <hip/hip_runtime.h>

#define TT 512
#define BB 64
#define IDIM 256
#define CDIM 512
#define NMEM 128
#define MDIM 64
#define KTOT 832     // (IDIM + M) + CDIM = 320 + 512
#define ODIM 576     // CDIM + M
#define NROWS 2048   // 4*CDIM
#define NA 256       // A-blocks
#define NB 64        // B-blocks

struct Params {
  const float* embs; const float* W_ih; const float* W_hh; const float* b_ih; const float* b_hh;
  const float* W_kr; const float* b_kr; const float* w_br; const float* W_kw; const float* b_kw;
  const float* w_bw; const float* W_e; const float* b_e; const float* W_a; const float* b_a;
  const float* h0; const float* c0; const float* r0; const float* mem0;
  float* out;
  unsigned* flags; // [0..256): A-write flags, [256..320): B flags, [320..576): A-read flags
  float* Wopt;   // [2048*832] reordered as [w][k][lr]
  float* h_buf;  // [2][B*CDIM] double buffered (st_wt writes, ld2_wt reads)
  float* r_buf;  // [B*M]                      (st_wt writes, ld2_wt reads)
};

__device__ __forceinline__ float sigmoidf_(float x) { return 1.0f / (1.0f + __expf(-x)); }
__device__ __forceinline__ float tanhf_(float x) {
  float e = __expf(-2.0f * fabsf(x));
  float t = (1.0f - e) / (1.0f + e);
  return copysignf(t, x);
}
__device__ __forceinline__ float softplusf_(float x) {
  return (x > 20.0f) ? x : log1pf(__expf(x));
}
__device__ __forceinline__ float wred_sum(float v) {
#pragma unroll
  for (int off = 32; off > 0; off >>= 1) v += __shfl_xor(v, off, 64);
  return v;
}
__device__ __forceinline__ float wred_max(float v) {
#pragma unroll
  for (int off = 32; off > 0; off >>= 1) v = fmaxf(v, __shfl_xor(v, off, 64));
  return v;
}
__device__ __forceinline__ unsigned wred_minu(unsigned v) {
#pragma unroll
  for (int off = 32; off > 0; off >>= 1) {
    unsigned o = (unsigned)__shfl_xor((int)v, off, 64);
    v = (o < v) ? o : v;
  }
  return v;
}

__device__ __forceinline__ unsigned flag_ld(const unsigned* f) {
  return __hip_atomic_load(f, __ATOMIC_RELAXED, __HIP_MEMORY_SCOPE_AGENT);
}
// Write-through store to the coherence point (same mechanism as the flag words).
__device__ __forceinline__ void st_wt(float* p, float v) {
  __hip_atomic_store(p, v, __ATOMIC_RELAXED, __HIP_MEMORY_SCOPE_AGENT);
}
__device__ __forceinline__ void flag_post(unsigned* f, unsigned val) {
  __hip_atomic_store(f, val, __ATOMIC_RELAXED, __HIP_MEMORY_SCOPE_AGENT);
}
__device__ __forceinline__ void drain_vm() {
  asm volatile("s_waitcnt vmcnt(0)" ::: "memory");
}
// Agent-coherent 8-byte data load (bypasses stale L2; same path the flags use).
__device__ __forceinline__ float2 ld2_wt(const float* p) {
  unsigned long long v = __hip_atomic_load((const unsigned long long*)p,
                                           __ATOMIC_RELAXED, __HIP_MEMORY_SCOPE_AGENT);
  float2 r;
  r.x = __uint_as_float((unsigned)(v & 0xFFFFFFFFull));
  r.y = __uint_as_float((unsigned)(v >> 32));
  return r;
}

// Poll 32 flags [base, base+32) until all >= target. Called by ALL waves.
__device__ __forceinline__ void wait_group32(const unsigned* base, int lane, unsigned target) {
  for (;;) {
    unsigned v = (lane < 32) ? flag_ld(base + lane) : 0xFFFFFFFFu;
    v = wred_minu(v);
    if (v >= target) break;
    __builtin_amdgcn_s_sleep(1);
  }
  asm volatile("" ::: "memory");
}
// Poll 256 flags (4 per lane), single wave. Caller must __syncthreads() after.
__device__ __forceinline__ void wait_all256(const unsigned* f, int lane, unsigned target) {
  const unsigned* fp = f + lane * 4;
  for (;;) {
    unsigned a0 = flag_ld(fp + 0);
    unsigned a1 = flag_ld(fp + 1);
    unsigned a2 = flag_ld(fp + 2);
    unsigned a3 = flag_ld(fp + 3);
    unsigned m = a0 < a1 ? a0 : a1;
    unsigned n = a2 < a3 ? a2 : a3;
    m = m < n ? m : n;
    m = wred_minu(m);
    if (m >= target) break;
    __builtin_amdgcn_s_sleep(1);
  }
  asm volatile("" ::: "memory");
}
// Poll 64 flags (1 per lane). Called by all waves.
__device__ __forceinline__ void wait_all64(const unsigned* f, int lane, unsigned target) {
  const unsigned* fp = f + lane;
  for (;;) {
    unsigned b = flag_ld(fp);
    b = wred_minu(b);
    if (b >= target) break;
    __builtin_amdgcn_s_sleep(1);
  }
  asm volatile("" ::: "memory");
}

// Pre-transpose combined weights into Wopt[(w*832 + k)*8 + lr],
// lr -> global gate row = 512*(lr>>1) + 2*w + (lr&1)
__global__ void __launch_bounds__(256) transpose_w_kernel(const float* __restrict__ W_ih,
                                                          const float* __restrict__ W_hh,
                                                          float* __restrict__ Wopt) {
  int idx = blockIdx.x * 256 + threadIdx.x;
  if (idx >= NROWS * KTOT) return;
  int lr = idx & 7;
  int rem = idx >> 3;          // w*832 + k
  int k = rem % KTOT;
  int w = rem / KTOT;
  int row = 512 * (lr >> 1) + 2 * w + (lr & 1);
  float v = (k < 320) ? W_ih[(size_t)row * 320 + k] : W_hh[(size_t)row * 512 + (k - 320)];
  Wopt[idx] = v;
}

// LDS overlay: a block is EITHER an A-block or a B-block; alias their arrays.
struct AShared {
  float xs[64 * 65];       // [kk][b] stride 65 (conflict-free); also reduce buf
  float wsa[KTOT * 8];     // resident weights [k][lr]
  float bsum[8];
};
struct BShared {
  float Mem[MDIM][NMEM + 1];  // [m][n] stride 129 (conflict-free)
  float hb[CDIM];
  float kw[MDIM], kr[MDIM], e[MDIM], a[MDIM];
  float ww[NMEM], wr[NMEM];
  float sc[8];  // 0:betaw 1:betar 2:|kw| 3:|kr| 4,5:max parts 6,7:sum parts
};
union SharedU { AShared a; BShared b; };

__global__ void __launch_bounds__(256) mann_kernel(Params p) {
  const int w = blockIdx.x;       // 0..255: A-blocks (c-dims {2w,2w+1}); 256..319: B-blocks
  const int tid = threadIdx.x;
  const int lane = tid & 63;
  const int q = tid >> 6;         // wave id 0..3

  unsigned* Aw = p.flags;         // 256 A-write flags
  unsigned* Bf = p.flags + 256;   // 64 B flags
  unsigned* Ar = p.flags + 320;   // 256 A-read flags

  __shared__ __align__(16) SharedU su;

  if (w < NA) {
    // ================= A path: gates GEMM + LSTM =================
    float* xs = su.a.xs;
    float* wsa = su.a.wsa;
    float* bsum = su.a.bsum;
    {
      const float4* src = (const float4*)(p.Wopt + (size_t)w * KTOT * 8);
      float4* dst = (float4*)wsa;
      for (int i = tid; i < KTOT * 2; i += 256) dst[i] = src[i];
    }
    if (tid < 8) {
      int row = 512 * (tid >> 1) + 2 * w + (tid & 1);
      bsum[tid] = p.b_ih[row] + p.b_hh[row];
    }
    float c_reg = 0.0f;  // tid<128: cell state for (b=tid&63, j=2w+(tid>>6))
    if (tid < 128) {
      int jj = tid >> 6, b = tid & 63;
      int j = 2 * w + jj;
      c_reg = p.c0[j];
      st_wt(p.h_buf + (size_t)b * CDIM + j, p.h0[j]);  // h_buf[0]
    }
    drain_vm();
    __syncthreads();
    if (tid == 0) {
      flag_post(&Aw[w], 1u);
      flag_post(&Ar[w], 1u);
    }

    const int kk4 = (tid & 15) * 4;
    const int bb0 = tid >> 4;

#pragma unroll 1
    for (int t = 0; t < TT; ++t) {
      // prefetch chunk 0 (embs: immutable) — no wait at step entry
      float4 vbuf[4];
#pragma unroll
      for (int i = 0; i < 4; ++i) {
        const int b = bb0 + 16 * i;
        vbuf[i] = *(const float4*)(p.embs + ((size_t)t * BB + b) * IDIM + kk4);
      }

      const float* h_read = p.h_buf + (size_t)(t & 1) * (BB * CDIM);
      float* h_write = p.h_buf + (size_t)((t + 1) & 1) * (BB * CDIM);

      float acc[8];
#pragma unroll
      for (int i = 0; i < 8; ++i) acc[i] = 0.0f;

      // ---- chunks 0..3 (emb), 5..12 (h) with per-group producer waits ----
      int cur = 0;
#pragma unroll 1
      for (int ci = 0; ci < 12; ++ci) {
#pragma unroll
        for (int i = 0; i < 4; ++i) {
          const int b = bb0 + 16 * i;
          xs[(kk4 + 0) * 65 + b] = vbuf[i].x;
          xs[(kk4 + 1) * 65 + b] = vbuf[i].y;
          xs[(kk4 + 2) * 65 + b] = vbuf[i].z;
          xs[(kk4 + 3) * 65 + b] = vbuf[i].w;
        }
        __syncthreads();

        const int nxt = (cur == 3) ? 5 : cur + 1;  // skip chunk 4 (r) -- deferred
        if (ci < 11) {
          if (nxt >= 5) {
            wait_group32(Aw + (nxt - 5) * 32, lane, (unsigned)(t + 1));
            const int k = nxt * 64 + kk4 - 320;
#pragma unroll
            for (int i = 0; i < 4; ++i) {
              const int b = bb0 + 16 * i;
              const float* src = h_read + (size_t)b * CDIM + k;
              const float2 lo = ld2_wt(src);
              const float2 hi = ld2_wt(src + 2);
              vbuf[i].x = lo.x; vbuf[i].y = lo.y; vbuf[i].z = hi.x; vbuf[i].w = hi.y;
            }
          } else {
            const int k = nxt * 64 + kk4;
#pragma unroll
            for (int i = 0; i < 4; ++i) {
              const int b = bb0 + 16 * i;
              vbuf[i] = *(const float4*)(p.embs + ((size_t)t * BB + b) * IDIM + k);
            }
          }
        }

        const int kkb = 16 * q;
#pragma unroll
        for (int kki = 0; kki < 16; ++kki) {
          const int kk = kkb + kki;
          const float xv = xs[kk * 65 + lane];
          const float4 w0 = *(const float4*)&wsa[(cur * 64 + kk) * 8];
          const float4 w1 = *(const float4*)&wsa[(cur * 64 + kk) * 8 + 4];
          acc[0] = fmaf(xv, w0.x, acc[0]);
          acc[1] = fmaf(xv, w0.y, acc[1]);
          acc[2] = fmaf(xv, w0.z, acc[2]);
          acc[3] = fmaf(xv, w0.w, acc[3]);
          acc[4] = fmaf(xv, w1.x, acc[4]);
          acc[5] = fmaf(xv, w1.y, acc[5]);
          acc[6] = fmaf(xv, w1.z, acc[6]);
          acc[7] = fmaf(xv, w1.w, acc[7]);
        }
        __syncthreads();
        cur = nxt;
      }

      // publish A-read: done reading h_read for step t
      if (tid == 0) flag_post(&Ar[w], (unsigned)(t + 2));

      // ---- r chunk: needs B(t-1) done ----
      wait_all64(Bf, lane, (unsigned)(t + 1));
      {
#pragma unroll
        for (int i = 0; i < 4; ++i) {
          const int b = bb0 + 16 * i;
          const float* src = p.r_buf + b * MDIM + kk4;
          const float2 lo = ld2_wt(src);
          const float2 hi = ld2_wt(src + 2);
          vbuf[i].x = lo.x; vbuf[i].y = lo.y; vbuf[i].z = hi.x; vbuf[i].w = hi.y;
        }
#pragma unroll
        for (int i = 0; i < 4; ++i) {
          const int b = bb0 + 16 * i;
          xs[(kk4 + 0) * 65 + b] = vbuf[i].x;
          xs[(kk4 + 1) * 65 + b] = vbuf[i].y;
          xs[(kk4 + 2) * 65 + b] = vbuf[i].z;
          xs[(kk4 + 3) * 65 + b] = vbuf[i].w;
        }
        __syncthreads();
        const int kkb = 16 * q;
#pragma unroll
        for (int kki = 0; kki < 16; ++kki) {
          const int kk = kkb + kki;
          const float xv = xs[kk * 65 + lane];
          const float4 w0 = *(const float4*)&wsa[(4 * 64 + kk) * 8];
          const float4 w1 = *(const float4*)&wsa[(4 * 64 + kk) * 8 + 4];
          acc[0] = fmaf(xv, w0.x, acc[0]);
          acc[1] = fmaf(xv, w0.y, acc[1]);
          acc[2] = fmaf(xv, w0.z, acc[2]);
          acc[3] = fmaf(xv, w0.w, acc[3]);
          acc[4] = fmaf(xv, w1.x, acc[4]);
          acc[5] = fmaf(xv, w1.y, acc[5]);
          acc[6] = fmaf(xv, w1.z, acc[6]);
          acc[7] = fmaf(xv, w1.w, acc[7]);
        }
        __syncthreads();
      }

      // cross-wave K reduction; WAR wait; LSTM
      {
        float* red = xs;  // [q][lr][b] = [4][8][64]
#pragma unroll
        for (int lr = 0; lr < 8; ++lr) red[(q * 8 + lr) * 64 + lane] = acc[lr];
        __syncthreads();
        if (tid < 64) wait_all256(Ar, lane, (unsigned)(t + 1));
        __syncthreads();
        if (tid < 128) {
          const int jj = tid >> 6, b = tid & 63;
          float g[4];
#pragma unroll
          for (int gate = 0; gate < 4; ++gate) {
            const int lr = gate * 2 + jj;
            float s = bsum[lr];
#pragma unroll
            for (int qq = 0; qq < 4; ++qq) s += red[(qq * 8 + lr) * 64 + b];
            g[gate] = s;
          }
          const float iv = sigmoidf_(g[0]);
          const float fv = sigmoidf_(g[1]);
          const float gv = tanhf_(g[2]);
          const float ov = sigmoidf_(g[3]);
          c_reg = fv * c_reg + iv * gv;
          const float hv = ov * tanhf_(c_reg);
          st_wt(h_write + (size_t)b * CDIM + 2 * w + jj, hv);
        }
      }
      drain_vm();
      __syncthreads();
      if (tid == 0) flag_post(&Aw[w], (unsigned)(t + 2));
    }
  } else {
    // ================= B path: heads + addressing + memory =================
    const int b = w - NA;
    float (&Mem_s)[MDIM][NMEM + 1] = su.b.Mem;
    float* hb = su.b.hb;
    float* kw_s = su.b.kw;
    float* kr_s = su.b.kr;
    float* e_s = su.b.e;
    float* a_s = su.b.a;
    float* ww_s = su.b.ww;
    float* wr_s = su.b.wr;
    float* sc = su.b.sc;

    for (int idx = tid; idx < NMEM * MDIM; idx += 256) {
      int n = idx >> 6, m = idx & 63;
      Mem_s[m][n] = p.mem0[idx];  // mem0[n][m] -> Mem_s[m][n]
    }
    if (tid < MDIM) st_wt(p.r_buf + b * MDIM + tid, p.r0[tid]);
    drain_vm();
    __syncthreads();
    if (tid == 0) flag_post(&Bf[b], 1u);

#pragma unroll 1
    for (int t = 0; t < TT; ++t) {
      float* h_src = p.h_buf + (size_t)((t + 1) & 1) * (BB * CDIM);  // h(t)

      // a = tanh(emb @ W_a^T + b_a) on wave 1 (overlaps wave 0's Aw poll)
      if (q == 1) {
        const int m = lane;
        const float* Wrow = p.W_a + (size_t)m * IDIM;
        const float* eb = p.embs + ((size_t)t * BB + b) * IDIM;
        float s = p.b_a[m];
#pragma unroll 4
        for (int k = 0; k < IDIM; k += 4) {
          const float4 wv = *(const float4*)(Wrow + k);
          const float4 ev = *(const float4*)(eb + k);
          s = fmaf(wv.x, ev.x, s);
          s = fmaf(wv.y, ev.y, s);
          s = fmaf(wv.z, ev.z, s);
          s = fmaf(wv.w, ev.w, s);
        }
        a_s[m] = tanhf_(s);
      }
      // wait for ALL producers' h(t) slices
      if (tid < 64) wait_all256(Aw, lane, (unsigned)(t + 2));
      __syncthreads();

      // stage h(t) (agent-coherent 8B loads)
      {
        const float2 hv = ld2_wt(h_src + (size_t)b * CDIM + tid * 2);
        hb[tid * 2] = hv.x;
        hb[tid * 2 + 1] = hv.y;
      }
      __syncthreads();
      // head GEMVs: [0,64):kw  [64,128):e  [128,192):kr  192:betaw 193:betar
      if (tid < 194) {
        const float* Wrow;
        if (tid < 64)        Wrow = p.W_kw + (size_t)tid * CDIM;
        else if (tid < 128)  Wrow = p.W_e + (size_t)(tid - 64) * CDIM;
        else if (tid < 192)  Wrow = p.W_kr + (size_t)(tid - 128) * CDIM;
        else if (tid == 192) Wrow = p.w_bw;
        else                 Wrow = p.w_br;
        float s = 0.0f;
#pragma unroll 4
        for (int k = 0; k < CDIM; k += 4) {
          const float4 wv = *(const float4*)(Wrow + k);
          s = fmaf(wv.x, hb[k], s);
          s = fmaf(wv.y, hb[k + 1], s);
          s = fmaf(wv.z, hb[k + 2], s);
          s = fmaf(wv.w, hb[k + 3], s);
        }
        if (tid < 64)       kw_s[tid] = tanhf_(s + p.b_kw[tid]);
        else if (tid < 128) e_s[tid - 64] = sigmoidf_(s + p.b_e[tid - 64]);
        else if (tid < 192) kr_s[tid - 128] = tanhf_(s + p.b_kr[tid - 128]);
        else                sc[tid - 192] = softplusf_(s);
      }
      __syncthreads();
      // key norms: wave0 -> |kw|, wave1 -> |kr|
      if (tid < 128) {
        const float v = (q == 0) ? kw_s[lane] : kr_s[lane];
        const float ss = wred_sum(v * v);
        if (lane == 0) sc[2 + q] = sqrtf(ss);
      }
      __syncthreads();
      // ---- write addressing (on old Mem) ----
      {
        float logit = 0.0f, ex = 0.0f;
        const float beta = sc[0], keyn = sc[2];
        if (tid < 128) {
          float sim = 0.0f, nrm = 0.0f;
#pragma unroll 8
          for (int m = 0; m < MDIM; ++m) {
            const float mv = Mem_s[m][tid];
            sim = fmaf(mv, kw_s[m], sim);
            nrm = fmaf(mv, mv, nrm);
          }
          logit = beta * sim / (sqrtf(nrm) * keyn + 1e-8f);
          const float mx = wred_max(logit);
          if (lane == 0) sc[4 + q] = mx;
        }
        __syncthreads();
        if (tid < 128) {
          ex = __expf(logit - fmaxf(sc[4], sc[5]));
          const float sm = wred_sum(ex);
          if (lane == 0) sc[6 + q] = sm;
        }
        __syncthreads();
        if (tid < 128) ww_s[tid] = ex / (sc[6] + sc[7]);
        __syncthreads();
      }
      // ---- memory write (erase/add) ----
      for (int idx = tid; idx < NMEM * MDIM; idx += 256) {
        const int m = idx >> 7, n = idx & 127;
        const float mv = Mem_s[m][n];
        Mem_s[m][n] = mv * (1.0f - ww_s[n] * e_s[m]) + ww_s[n] * a_s[m];
      }
      __syncthreads();
      // ---- read addressing (on new Mem) ----
      {
        float logit = 0.0f, ex = 0.0f;
        const float beta = sc[1], keyn = sc[3];
        if (tid < 128) {
          float sim = 0.0f, nrm = 0.0f;
#pragma unroll 8
          for (int m = 0; m < MDIM; ++m) {
            const float mv = Mem_s[m][tid];
            sim = fmaf(mv, kr_s[m], sim);
            nrm = fmaf(mv, mv, nrm);
          }
          logit = beta * sim / (sqrtf(nrm) * keyn + 1e-8f);
          const float mx = wred_max(logit);
          if (lane == 0) sc[4 + q] = mx;
        }
        __syncthreads();
        if (tid < 128) {
          ex = __expf(logit - fmaxf(sc[4], sc[5]));
          const float sm = wred_sum(ex);
          if (lane == 0) sc[6 + q] = sm;
        }
        __syncthreads();
        if (tid < 128) wr_s[tid] = ex / (sc[6] + sc[7]);
        __syncthreads();
      }
      // ---- read vector + outputs ----
      if (tid < 64) {
        float rv = 0.0f;
#pragma unroll 8
        for (int n = 0; n < NMEM; ++n) rv = fmaf(wr_s[n], Mem_s[tid][n], rv);
        st_wt(p.r_buf + b * MDIM + tid, rv);
        p.out[((size_t)t * BB + b) * ODIM + 512 + tid] = rv;
      }
      p.out[((size_t)t * BB + b) * ODIM + tid] = hb[tid];
      p.out[((size_t)t * BB + b) * ODIM + 256 + tid] = hb[tid + 256];
      // publish B (write-through drained, then private flag)
      drain_vm();
      __syncthreads();
      if (tid == 0) flag_post(&Bf[b], (unsigned)(t + 2));
    }
  }
}

extern "C" void kernel_launch(void* const* d_in, const int* in_sizes, int n_in,
                              void* d_out, int out_size, void* d_ws, size_t ws_size,
                              hipStream_t stream) {
  (void)in_sizes; (void)n_in; (void)out_size; (void)ws_size;
  Params p;
  p.embs = (const float*)d_in[0];
  p.W_ih = (const float*)d_in[1];
  p.W_hh = (const float*)d_in[2];
  p.b_ih = (const float*)d_in[3];
  p.b_hh = (const float*)d_in[4];
  p.W_kr = (const float*)d_in[5];
  p.b_kr = (const float*)d_in[6];
  p.w_br = (const float*)d_in[7];
  p.W_kw = (const float*)d_in[8];
  p.b_kw = (const float*)d_in[9];
  p.w_bw = (const float*)d_in[10];
  p.W_e  = (const float*)d_in[11];
  p.b_e  = (const float*)d_in[12];
  p.W_a  = (const float*)d_in[13];
  p.b_a  = (const float*)d_in[14];
  p.h0   = (const float*)d_in[15];
  p.c0   = (const float*)d_in[16];
  p.r0   = (const float*)d_in[17];
  p.mem0 = (const float*)d_in[18];
  p.out = (float*)d_out;

  float* ws = (float*)d_ws;
  p.flags = (unsigned*)ws;                  // 576 uints used, 1024 reserved
  p.Wopt = ws + 1024;                       // 2048*832      = 1,703,936 floats
  p.h_buf = p.Wopt + (size_t)NROWS * KTOT;  // 2*64*512      = 65,536 floats
  p.r_buf = p.h_buf + 2 * BB * CDIM;        // 64*64         = 4,096 floats

  hipMemsetAsync(p.flags, 0, 1024 * sizeof(unsigned), stream);

  const int total = NROWS * KTOT;
  hipLaunchKernelGGL(transpose_w_kernel, dim3((total + 255) / 256), dim3(256), 0, stream,
                     p.W_ih, p.W_hh, p.Wopt);

  void* kargs[] = { (void*)&p };
  hipError_t err = hipLaunchCooperativeKernel((const void*)mann_kernel, dim3(NA + NB), dim3(256),
                                              kargs, 0, stream);
  if (err != hipSuccess) {
    // All 320 blocks fit co-resident by construction (43.3 KB LDS -> 3 blocks/CU);
    // plain launch makes them all resident on an idle device.
    hipLaunchKernelGGL(mann_kernel, dim3(NA + NB), dim3(256), 0, stream, p);
  }
}

// Round 9
// 15251.190 us; speedup vs baseline: 1.8878x; 1.1022x over previous
//
#include <hip/hip_runtime.h>

#define TT 512
#define BB 64
#define IDIM 256
#define CDIM 512
#define NMEM 128
#define MDIM 64
#define KTOT 832     // (IDIM + M) + CDIM = 320 + 512
#define ODIM 576     // CDIM + M
#define NROWS 2048   // 4*CDIM
#define NA 256       // A-blocks
#define NB 64        // B-blocks
#define H16S 256     // u32 slots per batch row in h16 (CDIM/2)

struct Params {
  const float* embs; const float* W_ih; const float* W_hh; const float* b_ih; const float* b_hh;
  const float* W_kr; const float* b_kr; const float* w_br; const float* W_kw; const float* b_kw;
  const float* w_bw; const float* W_e; const float* b_e; const float* W_a; const float* b_a;
  const float* h0; const float* c0; const float* r0; const float* mem0;
  float* out;
  unsigned* flags; // [0..256): A-write flags, [256..320): B flags
  float* Wopt;     // [2048*832] reordered as [w][k][lr]
  unsigned* h16;   // [3][BB][H16S] bf16x2-packed h, triple buffered (agent atomics)
  float* r_buf;    // [B*M] (agent atomics)
};

__device__ __forceinline__ float sigmoidf_(float x) { return 1.0f / (1.0f + __expf(-x)); }
__device__ __forceinline__ float tanhf_(float x) {
  float e = __expf(-2.0f * fabsf(x));
  float t = (1.0f - e) / (1.0f + e);
  return copysignf(t, x);
}
__device__ __forceinline__ float softplusf_(float x) {
  return (x > 20.0f) ? x : log1pf(__expf(x));
}
__device__ __forceinline__ float wred_sum(float v) {
#pragma unroll
  for (int off = 32; off > 0; off >>= 1) v += __shfl_xor(v, off, 64);
  return v;
}
__device__ __forceinline__ float wred_max(float v) {
#pragma unroll
  for (int off = 32; off > 0; off >>= 1) v = fmaxf(v, __shfl_xor(v, off, 64));
  return v;
}
__device__ __forceinline__ unsigned wred_minu(unsigned v) {
#pragma unroll
  for (int off = 32; off > 0; off >>= 1) {
    unsigned o = (unsigned)__shfl_xor((int)v, off, 64);
    v = (o < v) ? o : v;
  }
  return v;
}

__device__ __forceinline__ unsigned flag_ld(const unsigned* f) {
  return __hip_atomic_load(f, __ATOMIC_RELAXED, __HIP_MEMORY_SCOPE_AGENT);
}
__device__ __forceinline__ void st_wt(float* p, float v) {
  __hip_atomic_store(p, v, __ATOMIC_RELAXED, __HIP_MEMORY_SCOPE_AGENT);
}
__device__ __forceinline__ void st_wt_u32(unsigned* p, unsigned v) {
  __hip_atomic_store(p, v, __ATOMIC_RELAXED, __HIP_MEMORY_SCOPE_AGENT);
}
__device__ __forceinline__ void flag_post(unsigned* f, unsigned val) {
  __hip_atomic_store(f, val, __ATOMIC_RELAXED, __HIP_MEMORY_SCOPE_AGENT);
}
__device__ __forceinline__ void drain_vm() {
  asm volatile("s_waitcnt vmcnt(0)" ::: "memory");
}
__device__ __forceinline__ float2 ld2_wt(const float* p) {
  unsigned long long v = __hip_atomic_load((const unsigned long long*)p,
                                           __ATOMIC_RELAXED, __HIP_MEMORY_SCOPE_AGENT);
  float2 r;
  r.x = __uint_as_float((unsigned)(v & 0xFFFFFFFFull));
  r.y = __uint_as_float((unsigned)(v >> 32));
  return r;
}
__device__ __forceinline__ unsigned long long ld_u64_wt(const unsigned* p) {
  return __hip_atomic_load((const unsigned long long*)p,
                           __ATOMIC_RELAXED, __HIP_MEMORY_SCOPE_AGENT);
}
__device__ __forceinline__ unsigned ld_u32_wt(const unsigned* p) {
  return __hip_atomic_load(p, __ATOMIC_RELAXED, __HIP_MEMORY_SCOPE_AGENT);
}
// f32 -> bf16 (round-to-nearest-even)
__device__ __forceinline__ unsigned f2bf(float x) {
  unsigned u = __float_as_uint(x);
  return (u + 0x7FFFu + ((u >> 16) & 1u)) >> 16;
}

// Poll 32 flags until all >= target (all waves call; lanes<32 load).
__device__ __forceinline__ void wait_group32(const unsigned* base, int lane, unsigned target) {
  for (;;) {
    unsigned v = (lane < 32) ? flag_ld(base + lane) : 0xFFFFFFFFu;
    v = wred_minu(v);
    if (v >= target) break;
    __builtin_amdgcn_s_sleep(1);
  }
  asm volatile("" ::: "memory");
}
// Poll 256 flags (4/lane), single wave. Caller must __syncthreads() after.
__device__ __forceinline__ void wait_all256(const unsigned* f, int lane, unsigned target) {
  const unsigned* fp = f + lane * 4;
  for (;;) {
    unsigned a0 = flag_ld(fp + 0);
    unsigned a1 = flag_ld(fp + 1);
    unsigned a2 = flag_ld(fp + 2);
    unsigned a3 = flag_ld(fp + 3);
    unsigned m = a0 < a1 ? a0 : a1;
    unsigned n = a2 < a3 ? a2 : a3;
    m = m < n ? m : n;
    m = wred_minu(m);
    if (m >= target) break;
    __builtin_amdgcn_s_sleep(1);
  }
  asm volatile("" ::: "memory");
}
// Poll 64 flags (1/lane), single wave. Caller must __syncthreads() after.
__device__ __forceinline__ void wait_all64(const unsigned* f, int lane, unsigned target) {
  const unsigned* fp = f + lane;
  for (;;) {
    unsigned b = flag_ld(fp);
    b = wred_minu(b);
    if (b >= target) break;
    __builtin_amdgcn_s_sleep(1);
  }
  asm volatile("" ::: "memory");
}

// Wopt[(w*832 + k)*8 + lr], lr -> row = 512*(lr>>1) + 2*w + (lr&1)
__global__ void __launch_bounds__(256) transpose_w_kernel(const float* __restrict__ W_ih,
                                                          const float* __restrict__ W_hh,
                                                          float* __restrict__ Wopt) {
  int idx = blockIdx.x * 256 + threadIdx.x;
  if (idx >= NROWS * KTOT) return;
  int lr = idx & 7;
  int rem = idx >> 3;          // w*832 + k
  int k = rem % KTOT;
  int w = rem / KTOT;
  int row = 512 * (lr >> 1) + 2 * w + (lr & 1);
  float v = (k < 320) ? W_ih[(size_t)row * 320 + k] : W_hh[(size_t)row * 512 + (k - 320)];
  Wopt[idx] = v;
}

// LDS overlay: a block is EITHER an A-block or a B-block.
struct AShared {
  float xs[64 * 65];       // [kk][b] stride 65; also reduce buf
  float wsa[KTOT * 8];     // resident weights [k][lr]
  float bsum[8];
};
struct BShared {
  float Mem[MDIM][NMEM + 1];
  float hb[CDIM];
  float kw[MDIM], kr[MDIM], e[MDIM], a[MDIM];
  float ww[NMEM], wr[NMEM];
  float sc[8];
};
union SharedU { AShared a; BShared b; };

__global__ void __launch_bounds__(256) mann_kernel(Params p) {
  const int w = blockIdx.x;
  const int tid = threadIdx.x;
  const int lane = tid & 63;
  const int q = tid >> 6;

  unsigned* Aw = p.flags;         // 256 A-write flags
  unsigned* Bf = p.flags + 256;   // 64 B flags

  __shared__ __align__(16) SharedU su;

  if (w < NA) {
    // ================= A path: gates GEMM + LSTM =================
    float* xs = su.a.xs;
    float* wsa = su.a.wsa;
    float* bsum = su.a.bsum;
    {
      const float4* src = (const float4*)(p.Wopt + (size_t)w * KTOT * 8);
      float4* dst = (float4*)wsa;
      for (int i = tid; i < KTOT * 2; i += 256) dst[i] = src[i];
    }
    if (tid < 8) {
      int row = 512 * (tid >> 1) + 2 * w + (tid & 1);
      bsum[tid] = p.b_ih[row] + p.b_hh[row];
    }
    float2 c2 = make_float2(0.0f, 0.0f);  // tid<64: cell state for (b=tid, j=2w / 2w+1)
    if (tid < 64) {
      c2 = make_float2(p.c0[2 * w], p.c0[2 * w + 1]);
      unsigned pk = f2bf(p.h0[2 * w]) | (f2bf(p.h0[2 * w + 1]) << 16);
      st_wt_u32(p.h16 + (size_t)tid * H16S + w, pk);  // h16[0][b=tid][w]
    }
    drain_vm();
    __syncthreads();
    if (tid == 0) flag_post(&Aw[w], 1u);

    const int kk4 = (tid & 15) * 4;
    const int bb0 = tid >> 4;

#pragma unroll 1
    for (int t = 0; t < TT; ++t) {
      const unsigned* h16r = p.h16 + (size_t)(t % 3) * (BB * H16S);
      unsigned* h16w = p.h16 + (size_t)((t + 1) % 3) * (BB * H16S);
      const unsigned tgt = (unsigned)(t + 1);

      float4 ev[2][4];          // emb staging (2-deep)
      unsigned long long hv[2][4];  // h staging (2-deep, bf16x4 per u64)

      // issue loads for chunk cn into buffer s
      auto issue = [&](int cn, int s) {
        if (cn < 4) {
          const int k = cn * 64 + kk4;
#pragma unroll
          for (int i = 0; i < 4; ++i) {
            const int b = bb0 + 16 * i;
            ev[s][i] = *(const float4*)(p.embs + ((size_t)t * BB + b) * IDIM + k);
          }
        } else {
          wait_group32(Aw + (cn - 5) * 32, lane, tgt);
          const int slot = (cn * 32 - 160) + (tid & 15) * 2;
#pragma unroll
          for (int i = 0; i < 4; ++i) {
            const int b = bb0 + 16 * i;
            hv[s][i] = ld_u64_wt(h16r + (size_t)b * H16S + slot);
          }
        }
      };
      // stage buffer s (chunk cn) into xs
      auto stage = [&](int cn, int s) {
        if (cn < 4) {
#pragma unroll
          for (int i = 0; i < 4; ++i) {
            const int b = bb0 + 16 * i;
            xs[(kk4 + 0) * 65 + b] = ev[s][i].x;
            xs[(kk4 + 1) * 65 + b] = ev[s][i].y;
            xs[(kk4 + 2) * 65 + b] = ev[s][i].z;
            xs[(kk4 + 3) * 65 + b] = ev[s][i].w;
          }
        } else {
#pragma unroll
          for (int i = 0; i < 4; ++i) {
            const int b = bb0 + 16 * i;
            const unsigned lo = (unsigned)hv[s][i];
            const unsigned hi = (unsigned)(hv[s][i] >> 32);
            xs[(kk4 + 0) * 65 + b] = __uint_as_float(lo << 16);
            xs[(kk4 + 1) * 65 + b] = __uint_as_float(lo & 0xFFFF0000u);
            xs[(kk4 + 2) * 65 + b] = __uint_as_float(hi << 16);
            xs[(kk4 + 3) * 65 + b] = __uint_as_float(hi & 0xFFFF0000u);
          }
        }
      };

      float acc[8];
#pragma unroll
      for (int i = 0; i < 8; ++i) acc[i] = 0.0f;

      auto compute = [&](int cn) {
        const int kkb = 16 * q;
#pragma unroll
        for (int kki = 0; kki < 16; ++kki) {
          const int kk = kkb + kki;
          const float xv = xs[kk * 65 + lane];
          const float4 w0 = *(const float4*)&wsa[(cn * 64 + kk) * 8];
          const float4 w1 = *(const float4*)&wsa[(cn * 64 + kk) * 8 + 4];
          acc[0] = fmaf(xv, w0.x, acc[0]);
          acc[1] = fmaf(xv, w0.y, acc[1]);
          acc[2] = fmaf(xv, w0.z, acc[2]);
          acc[3] = fmaf(xv, w0.w, acc[3]);
          acc[4] = fmaf(xv, w1.x, acc[4]);
          acc[5] = fmaf(xv, w1.y, acc[5]);
          acc[6] = fmaf(xv, w1.z, acc[6]);
          acc[7] = fmaf(xv, w1.w, acc[7]);
        }
      };

      // ---- chunks {0,1,2,3,5..12} with 2-deep prefetch ----
      issue(0, 0);
      issue(1, 1);
#pragma unroll 1
      for (int ci = 0; ci < 12; ++ci) {
        const int cn = ci + (ci >= 4 ? 1 : 0);
        stage(cn, ci & 1);
        __syncthreads();
        if (ci < 10) {
          const int cn2 = (ci + 2) + (ci + 2 >= 4 ? 1 : 0);
          issue(cn2, ci & 1);
        }
        compute(cn);
        __syncthreads();
      }

      // ---- r chunk (4): needs B(t-1) done; wave0 polls ----
      if (tid < 64) wait_all64(Bf, lane, tgt);
      __syncthreads();
      {
#pragma unroll
        for (int i = 0; i < 4; ++i) {
          const int b = bb0 + 16 * i;
          const float* src = p.r_buf + b * MDIM + kk4;
          const float2 lo = ld2_wt(src);
          const float2 hi = ld2_wt(src + 2);
          xs[(kk4 + 0) * 65 + b] = lo.x;
          xs[(kk4 + 1) * 65 + b] = lo.y;
          xs[(kk4 + 2) * 65 + b] = hi.x;
          xs[(kk4 + 3) * 65 + b] = hi.y;
        }
        __syncthreads();
        compute(4);
        __syncthreads();
      }

      // ---- cross-wave K reduction + LSTM (tid<64 owns both j=2w,2w+1) ----
      {
        float* red = xs;  // [q][lr][b]
#pragma unroll
        for (int lr = 0; lr < 8; ++lr) red[(q * 8 + lr) * 64 + lane] = acc[lr];
        __syncthreads();
        if (tid < 64) {
          const int b = tid;
          float g[8];
#pragma unroll
          for (int lr = 0; lr < 8; ++lr) {
            float s = bsum[lr];
#pragma unroll
            for (int qq = 0; qq < 4; ++qq) s += red[(qq * 8 + lr) * 64 + b];
            g[lr] = s;
          }
          // lr = 2*gate + jj; gates: 0=i 1=f 2=g 3=o
          const float i0 = sigmoidf_(g[0]), f0 = sigmoidf_(g[2]);
          const float g0 = tanhf_(g[4]), o0 = sigmoidf_(g[6]);
          const float i1 = sigmoidf_(g[1]), f1 = sigmoidf_(g[3]);
          const float g1 = tanhf_(g[5]), o1 = sigmoidf_(g[7]);
          c2.x = f0 * c2.x + i0 * g0;
          c2.y = f1 * c2.y + i1 * g1;
          const float h0 = o0 * tanhf_(c2.x);
          const float h1 = o1 * tanhf_(c2.y);
          const unsigned pk = f2bf(h0) | (f2bf(h1) << 16);
          st_wt_u32(h16w + (size_t)b * H16S + w, pk);
        }
      }
      drain_vm();
      __syncthreads();
      if (tid == 0) flag_post(&Aw[w], (unsigned)(t + 2));
    }
  } else {
    // ================= B path: heads + addressing + memory =================
    const int b = w - NA;
    float (&Mem_s)[MDIM][NMEM + 1] = su.b.Mem;
    float* hb = su.b.hb;
    float* kw_s = su.b.kw;
    float* kr_s = su.b.kr;
    float* e_s = su.b.e;
    float* a_s = su.b.a;
    float* ww_s = su.b.ww;
    float* wr_s = su.b.wr;
    float* sc = su.b.sc;

    for (int idx = tid; idx < NMEM * MDIM; idx += 256) {
      int n = idx >> 6, m = idx & 63;
      Mem_s[m][n] = p.mem0[idx];
    }
    if (tid < MDIM) st_wt(p.r_buf + b * MDIM + tid, p.r0[tid]);
    drain_vm();
    __syncthreads();
    if (tid == 0) flag_post(&Bf[b], 1u);

#pragma unroll 1
    for (int t = 0; t < TT; ++t) {
      const unsigned* hsrc = p.h16 + (size_t)((t + 1) % 3) * (BB * H16S) + (size_t)b * H16S;

      // a = tanh(emb @ W_a^T + b_a) on wave 1 (overlaps wave 0's Aw poll)
      if (q == 1) {
        const int m = lane;
        const float* Wrow = p.W_a + (size_t)m * IDIM;
        const float* eb = p.embs + ((size_t)t * BB + b) * IDIM;
        float s = p.b_a[m];
#pragma unroll 4
        for (int k = 0; k < IDIM; k += 4) {
          const float4 wv = *(const float4*)(Wrow + k);
          const float4 evv = *(const float4*)(eb + k);
          s = fmaf(wv.x, evv.x, s);
          s = fmaf(wv.y, evv.y, s);
          s = fmaf(wv.z, evv.z, s);
          s = fmaf(wv.w, evv.w, s);
        }
        a_s[m] = tanhf_(s);
      }
      if (tid < 64) wait_all256(Aw, lane, (unsigned)(t + 2));
      __syncthreads();

      // stage h(t): one u32 (2 bf16) per thread
      {
        const unsigned v = ld_u32_wt(hsrc + tid);
        hb[2 * tid] = __uint_as_float(v << 16);
        hb[2 * tid + 1] = __uint_as_float(v & 0xFFFF0000u);
      }
      __syncthreads();
      // head GEMVs: [0,64):kw  [64,128):e  [128,192):kr  192:betaw 193:betar
      if (tid < 194) {
        const float* Wrow;
        if (tid < 64)        Wrow = p.W_kw + (size_t)tid * CDIM;
        else if (tid < 128)  Wrow = p.W_e + (size_t)(tid - 64) * CDIM;
        else if (tid < 192)  Wrow = p.W_kr + (size_t)(tid - 128) * CDIM;
        else if (tid == 192) Wrow = p.w_bw;
        else                 Wrow = p.w_br;
        float s = 0.0f;
#pragma unroll 4
        for (int k = 0; k < CDIM; k += 4) {
          const float4 wv = *(const float4*)(Wrow + k);
          s = fmaf(wv.x, hb[k], s);
          s = fmaf(wv.y, hb[k + 1], s);
          s = fmaf(wv.z, hb[k + 2], s);
          s = fmaf(wv.w, hb[k + 3], s);
        }
        if (tid < 64)       kw_s[tid] = tanhf_(s + p.b_kw[tid]);
        else if (tid < 128) e_s[tid - 64] = sigmoidf_(s + p.b_e[tid - 64]);
        else if (tid < 192) kr_s[tid - 128] = tanhf_(s + p.b_kr[tid - 128]);
        else                sc[tid - 192] = softplusf_(s);
      }
      __syncthreads();
      if (tid < 128) {
        const float v = (q == 0) ? kw_s[lane] : kr_s[lane];
        const float ss = wred_sum(v * v);
        if (lane == 0) sc[2 + q] = sqrtf(ss);
      }
      __syncthreads();
      // ---- write addressing (old Mem) ----
      {
        float logit = 0.0f, ex = 0.0f;
        const float beta = sc[0], keyn = sc[2];
        if (tid < 128) {
          float sim = 0.0f, nrm = 0.0f;
#pragma unroll 8
          for (int m = 0; m < MDIM; ++m) {
            const float mv = Mem_s[m][tid];
            sim = fmaf(mv, kw_s[m], sim);
            nrm = fmaf(mv, mv, nrm);
          }
          logit = beta * sim / (sqrtf(nrm) * keyn + 1e-8f);
          const float mx = wred_max(logit);
          if (lane == 0) sc[4 + q] = mx;
        }
        __syncthreads();
        if (tid < 128) {
          ex = __expf(logit - fmaxf(sc[4], sc[5]));
          const float sm = wred_sum(ex);
          if (lane == 0) sc[6 + q] = sm;
        }
        __syncthreads();
        if (tid < 128) ww_s[tid] = ex / (sc[6] + sc[7]);
        __syncthreads();
      }
      // ---- memory write (erase/add) ----
      for (int idx = tid; idx < NMEM * MDIM; idx += 256) {
        const int m = idx >> 7, n = idx & 127;
        const float mv = Mem_s[m][n];
        Mem_s[m][n] = mv * (1.0f - ww_s[n] * e_s[m]) + ww_s[n] * a_s[m];
      }
      __syncthreads();
      // ---- read addressing (new Mem) ----
      {
        float logit = 0.0f, ex = 0.0f;
        const float beta = sc[1], keyn = sc[3];
        if (tid < 128) {
          float sim = 0.0f, nrm = 0.0f;
#pragma unroll 8
          for (int m = 0; m < MDIM; ++m) {
            const float mv = Mem_s[m][tid];
            sim = fmaf(mv, kr_s[m], sim);
            nrm = fmaf(mv, mv, nrm);
          }
          logit = beta * sim / (sqrtf(nrm) * keyn + 1e-8f);
          const float mx = wred_max(logit);
          if (lane == 0) sc[4 + q] = mx;
        }
        __syncthreads();
        if (tid < 128) {
          ex = __expf(logit - fmaxf(sc[4], sc[5]));
          const float sm = wred_sum(ex);
          if (lane == 0) sc[6 + q] = sm;
        }
        __syncthreads();
        if (tid < 128) wr_s[tid] = ex / (sc[6] + sc[7]);
        __syncthreads();
      }
      // ---- read vector; publish Bf EARLY (before out writes) ----
      float rv = 0.0f;
      if (tid < 64) {
#pragma unroll 8
        for (int n = 0; n < NMEM; ++n) rv = fmaf(wr_s[n], Mem_s[tid][n], rv);
        st_wt(p.r_buf + b * MDIM + tid, rv);
      }
      drain_vm();
      __syncthreads();
      if (tid == 0) flag_post(&Bf[b], (unsigned)(t + 2));
      // ---- outputs (off critical path) ----
      if (tid < 64) p.out[((size_t)t * BB + b) * ODIM + 512 + tid] = rv;
      p.out[((size_t)t * BB + b) * ODIM + tid] = hb[tid];
      p.out[((size_t)t * BB + b) * ODIM + 256 + tid] = hb[tid + 256];
    }
  }
}

extern "C" void kernel_launch(void* const* d_in, const int* in_sizes, int n_in,
                              void* d_out, int out_size, void* d_ws, size_t ws_size,
                              hipStream_t stream) {
  (void)in_sizes; (void)n_in; (void)out_size; (void)ws_size;
  Params p;
  p.embs = (const float*)d_in[0];
  p.W_ih = (const float*)d_in[1];
  p.W_hh = (const float*)d_in[2];
  p.b_ih = (const float*)d_in[3];
  p.b_hh = (const float*)d_in[4];
  p.W_kr = (const float*)d_in[5];
  p.b_kr = (const float*)d_in[6];
  p.w_br = (const float*)d_in[7];
  p.W_kw = (const float*)d_in[8];
  p.b_kw = (const float*)d_in[9];
  p.w_bw = (const float*)d_in[10];
  p.W_e  = (const float*)d_in[11];
  p.b_e  = (const float*)d_in[12];
  p.W_a  = (const float*)d_in[13];
  p.b_a  = (const float*)d_in[14];
  p.h0   = (const float*)d_in[15];
  p.c0   = (const float*)d_in[16];
  p.r0   = (const float*)d_in[17];
  p.mem0 = (const float*)d_in[18];
  p.out = (float*)d_out;

  float* ws = (float*)d_ws;
  p.flags = (unsigned*)ws;                          // 320 uints used, 1024 reserved
  p.Wopt = ws + 1024;                               // 1,703,936 floats
  p.h16 = (unsigned*)(p.Wopt + (size_t)NROWS * KTOT);  // 3*64*256 = 49,152 u32
  p.r_buf = (float*)(p.h16 + 3 * BB * H16S);        // 4,096 floats

  hipMemsetAsync(p.flags, 0, 1024 * sizeof(unsigned), stream);

  const int total = NROWS * KTOT;
  hipLaunchKernelGGL(transpose_w_kernel, dim3((total + 255) / 256), dim3(256), 0, stream,
                     p.W_ih, p.W_hh, p.Wopt);

  void* kargs[] = { (void*)&p };
  hipError_t err = hipLaunchCooperativeKernel((const void*)mann_kernel, dim3(NA + NB), dim3(256),
                                              kargs, 0, stream);
  if (err != hipSuccess) {
    // 43.3 KB LDS -> >=2 blocks/CU; all 320 blocks co-resident on an idle device.
    hipLaunchKernelGGL(mann_kernel, dim3(NA + NB), dim3(256), 0, stream, p);
  }
}